// Round 1
// 2484.311 us; speedup vs baseline: 1.1375x; 1.1375x over previous
//
#include <hip/hip_runtime.h>

#define L_SZ 2048
#define DIM_SZ 512
#define SPADK 1088   // mp logits row: 513 mag + 513 phase + 62 pad
#define ATK 544      // symmetric iSTFT GEMM K: 513 padded to 17*32
#define ATM 576      // symmetric iSTFT GEMM M: 513 padded to 9*64
#define ATSZ (ATM * ATK)   // 313344 elems per table

// ---------------- per-batch LoRA factor GEMVs: out[b*rows + r] = dot(mat[r], g[b]) ----
__global__ __launch_bounds__(256) void lora_vec_k(const float* __restrict__ mat, int rows,
                                                  const float* __restrict__ g,
                                                  float* __restrict__ out) {
  __shared__ float gs[2048];
  int tid = threadIdx.x;
#pragma unroll
  for (int i = 0; i < 8; i++) gs[i * 256 + tid] = g[i * 256 + tid];
  __syncthreads();
  int row = blockIdx.x * 4 + (tid >> 6);
  if (row >= rows) return;
  int lane = tid & 63;
  float4 mv = *(const float4*)(mat + (size_t)row * 256 + lane * 4);
  float p[8];
#pragma unroll
  for (int b = 0; b < 8; b++) {
    const float* gb = gs + b * 256 + lane * 4;
    p[b] = mv.x * gb[0] + mv.y * gb[1] + mv.z * gb[2] + mv.w * gb[3];
  }
#pragma unroll
  for (int b = 0; b < 8; b++) {
    float v = p[b];
#pragma unroll
    for (int off = 32; off > 0; off >>= 1) v += __shfl_down(v, off, 64);
    if (lane == 0) out[(size_t)b * rows + row] = v;
  }
}

// ------- W_eff[b][m][k] = W[m][k] + sum_r aout[b][r*M+m] * ain[b][k*R+r]  (fp32) -------
__global__ __launch_bounds__(256) void weff_k(const float* __restrict__ W,
                                              const float* __restrict__ ain,
                                              const float* __restrict__ aout,
                                              float* __restrict__ out, int M, int Mpad,
                                              int K, int R) {
  int b = blockIdx.z;
  size_t flat = (size_t)blockIdx.x * 256 + threadIdx.x;  // over Mpad*K (exact multiple)
  int m = (int)(flat / K), k = (int)(flat % K);
  float v = 0.f;
  if (m < M) {
    v = W[(size_t)m * K + k];
    const float* ai = ain + ((size_t)b * K + k) * R;
    const float* ao = aout + (size_t)b * M * R + m;
    for (int r = 0; r < R; r++) v += ai[r] * ao[(size_t)r * M];
  }
  out[((size_t)b * Mpad + m) * K + k] = v;
}

// -------- causal depthwise conv: h0[b][t][c] = sum_k w[c][k] * x[b][c][t-k]  (fp32) ----
__global__ __launch_bounds__(256) void dconv_k(const float* __restrict__ x,
                                               const float* __restrict__ w,
                                               const float* __restrict__ bias,
                                               float* __restrict__ h0) {
  const int t0 = blockIdx.x * 64;
  const int c0 = blockIdx.y * 64;
  const int b = blockIdx.z;
  const int tid = threadIdx.x;
  __shared__ float xs[64 * 68];
  const float* xb = x + ((size_t)b * DIM_SZ + c0) * L_SZ;
#pragma unroll
  for (int i = 0; i < 17; i++) {
    int flat = i * 256 + tid;  // 0..4351 = 64*68
    int c = flat / 68, tt = flat % 68;
    int t = t0 - 4 + tt;
    xs[c * 68 + tt] = (t >= 0) ? xb[(size_t)c * L_SZ + t] : 0.0f;
  }
  __syncthreads();
  int c = tid & 63;
  int tb = (tid >> 6) * 16;
  float wl[5];
#pragma unroll
  for (int k = 0; k < 5; k++) wl[k] = w[(c0 + c) * 5 + k];
  float bl = bias[c0 + c];
  float* o = h0 + ((size_t)b * L_SZ + t0 + tb) * DIM_SZ + c0 + c;
#pragma unroll
  for (int j = 0; j < 16; j++) {
    int t = tb + j;
    float acc = bl;
#pragma unroll
    for (int k = 0; k < 5; k++) acc += wl[k] * xs[c * 68 + t + 4 - k];
    o[(size_t)j * DIM_SZ] = acc;
  }
}

// ---- symmetric istft basis tables (window + sideband weights folded), fp32; + win ----
// table 0: Ac[n][k] = wn[n] * wk_k * cos(2*pi*k*n/1024)   (n,k in 0..512, rest 0)
// table 1: As[n][k] = wn[n] * 2    * sin(2*pi*k*n/1024)
// x[n]      = C[n] - D[n]   (n <= 512)
// x[1024-n] = C[n] + D[n]   (n >= 1..511; uses wn symmetry wn[1024-n]=wn[n])
__global__ __launch_bounds__(256) void atab2_k(float* __restrict__ A,
                                               double* __restrict__ win) {
  int flat = blockIdx.x * 256 + threadIdx.x;  // over 2*576*544 = 626688
  int table = flat / ATSZ;
  int rem = flat - table * ATSZ;
  int n = rem / ATK, k = rem % ATK;
  const double W = 6.283185307179586476925287 / 1024.0;
  float val = 0.f;
  if (n <= 512 && k <= 512) {
    double wn = 0.5 * (1.0 - cos(W * (double)n));
    int mm = (k * n) & 1023;
    if (table == 0) {
      double wk = (k == 0 || k == 512) ? 1.0 : 2.0;
      val = (float)(wn * wk * cos(W * (double)mm));
    } else {
      val = (float)(wn * 2.0 * sin(W * (double)mm));
    }
  }
  A[flat] = val;
  if (flat < 1024) win[flat] = 0.5 * (1.0 - cos(W * (double)flat));
}

// ------- S prep: read fp32 (m,p) logits row, write Sre = mag*cos(p), Sim = mag*sin(p) --
__global__ __launch_bounds__(256) void sprep2_k(const float* __restrict__ mp,
                                                float* __restrict__ Sre,
                                                float* __restrict__ Sim) {
  size_t flat = (size_t)blockIdx.x * 256 + threadIdx.x;  // over 8*2048*544
  size_t row = flat / ATK;
  int k = (int)(flat % ATK);
  float re = 0.f, im = 0.f;
  if (k < 513) {
    const float* r = mp + row * SPADK;
    float m = r[k], p = r[513 + k];
    float mag = fminf(expf(m), 100.0f);
    re = mag * cosf(p);
    im = mag * sinf(p);
  }
  Sre[row * ATK + k] = re;
  Sim[row * ATK + k] = im;
}

// ---- plain fp32 LDS-tiled GEMM: C[b][t][m] = act( sum_k A[b][m][k]*B[b][t][k] + bias )
template <bool GELU>
__global__ __launch_bounds__(256) void gemm32(const float* __restrict__ A, size_t a_bs,
                                              const float* __restrict__ Bm, size_t b_bs,
                                              const float* __restrict__ bias, int Mb,
                                              float* __restrict__ C, size_t c_bs, int ldc,
                                              int Mst, int K) {
  const int b = blockIdx.z;
  const int m0 = blockIdx.x * 64;
  const int t0 = blockIdx.y * 64;
  const int tid = threadIdx.x;
  __shared__ float As[64][33];
  __shared__ float Bs[64][33];
  const float* Ab = A + (size_t)b * a_bs + (size_t)m0 * K;
  const float* Bb = Bm + (size_t)b * b_bs + (size_t)t0 * K;
  const int tm = tid & 15;   // m-subtile
  const int tt = tid >> 4;   // t-subtile
  float acc[4][4] = {};
  for (int kt = 0; kt < K; kt += 32) {
#pragma unroll
    for (int i = 0; i < 2; i++) {
      int ch = i * 256 + tid;            // 0..511
      int row = ch >> 3, kc = (ch & 7) * 4;
      *(float4*)(&As[row][kc]) = *(const float4*)(Ab + (size_t)row * K + kt + kc);
      *(float4*)(&Bs[row][kc]) = *(const float4*)(Bb + (size_t)row * K + kt + kc);
    }
    __syncthreads();
#pragma unroll 8
    for (int kk = 0; kk < 32; kk++) {
      float am[4], bv[4];
#pragma unroll
      for (int i = 0; i < 4; i++) am[i] = As[tm * 4 + i][kk];
#pragma unroll
      for (int j = 0; j < 4; j++) bv[j] = Bs[tt * 4 + j][kk];
#pragma unroll
      for (int i = 0; i < 4; i++)
#pragma unroll
        for (int j = 0; j < 4; j++) acc[i][j] += am[i] * bv[j];
    }
    __syncthreads();
  }
  if (m0 + tm * 4 >= Mst) return;  // clip padded A rows
#pragma unroll
  for (int j = 0; j < 4; j++) {
    float4 v4;
    float* vp = &v4.x;
#pragma unroll
    for (int i = 0; i < 4; i++) {
      float v = acc[i][j];
      int m = m0 + tm * 4 + i;
      if (bias != nullptr && m < Mb) v += bias[m];
      if (GELU) v = 0.5f * v * (1.0f + erff(v * 0.70710678118654752f));
      vp[i] = v;
    }
    *(float4*)(C + (size_t)b * c_bs + (size_t)(t0 + tt * 4 + j) * ldc + m0 + tm * 4) = v4;
  }
}

// ---- symmetric iSTFT GEMM with FP64 ACCUMULATION:
//      C[b][t][m] = sum_k A[m][k] * S[b][t][k], M = 576 (513 valid), K = 544 (513 valid)
__global__ __launch_bounds__(256) void gemm64s(const float* __restrict__ A,
                                               const float* __restrict__ Bm, size_t b_bs,
                                               float* __restrict__ C, size_t c_bs,
                                               int ldc, int K) {
  const int b = blockIdx.z;
  const int m0 = blockIdx.x * 64;
  const int t0 = blockIdx.y * 64;
  const int tid = threadIdx.x;
  __shared__ float As[64][33];
  __shared__ float Bs[64][33];
  const float* Ab = A + (size_t)m0 * K;
  const float* Bb = Bm + (size_t)b * b_bs + (size_t)t0 * K;
  const int tm = tid & 15;
  const int tt = tid >> 4;
  double acc[4][4] = {};
  for (int kt = 0; kt < K; kt += 32) {
#pragma unroll
    for (int i = 0; i < 2; i++) {
      int ch = i * 256 + tid;
      int row = ch >> 3, kc = (ch & 7) * 4;
      *(float4*)(&As[row][kc]) = *(const float4*)(Ab + (size_t)row * K + kt + kc);
      *(float4*)(&Bs[row][kc]) = *(const float4*)(Bb + (size_t)row * K + kt + kc);
    }
    __syncthreads();
#pragma unroll 4
    for (int kk = 0; kk < 32; kk++) {
      double am[4], bv[4];
#pragma unroll
      for (int i = 0; i < 4; i++) am[i] = (double)As[tm * 4 + i][kk];
#pragma unroll
      for (int j = 0; j < 4; j++) bv[j] = (double)Bs[tt * 4 + j][kk];
#pragma unroll
      for (int i = 0; i < 4; i++)
#pragma unroll
        for (int j = 0; j < 4; j++) acc[i][j] = fma(am[i], bv[j], acc[i][j]);
    }
    __syncthreads();
  }
#pragma unroll
  for (int j = 0; j < 4; j++) {
    float4 v4;
    float* vp = &v4.x;
#pragma unroll
    for (int i = 0; i < 4; i++) vp[i] = (float)acc[i][j];
    *(float4*)(C + (size_t)b * c_bs + (size_t)(t0 + tt * 4 + j) * ldc + m0 + tm * 4) = v4;
  }
}

// ------- overlap-add + env normalize + crop, with symmetric frame reconstruction:
//   frame[tau][n] = C[tau][n] - D[tau][n]            (n <= 512)
//                 = C[tau][1024-n] + D[tau][1024-n]  (n >= 513)
// (window is folded into C/D via the basis tables; wn is symmetric so both halves share it)
__global__ __launch_bounds__(256) void ola_k(const float* __restrict__ CD,
                                             const double* __restrict__ win,
                                             float* __restrict__ out) {
  size_t flat = (size_t)blockIdx.x * 256 + threadIdx.x;  // over 8*524288
  int b = (int)(flat >> 19);
  int t = (int)(flat & 524287);
  int g = t + 384;  // PAD
  int r = g & 255, q4 = g >> 8;
  double acc = 0.0, env = 0.0;
#pragma unroll
  for (int q = 0; q < 4; q++) {
    int tau = q4 - q;
    int n = r + 256 * q;
    if (tau >= 0 && tau < 2048) {
      double w = win[n];
      int np = (n <= 512) ? n : 1024 - n;
      double sgn = (n <= 512) ? -1.0 : 1.0;
      const float* base = CD + ((size_t)b * 2048 + tau) * 1152 + np;
      acc += (double)base[0] + sgn * (double)base[576];
      env = fma(w, w, env);
    }
  }
  out[flat] = (float)(acc / (env * 1024.0));
}

extern "C" void kernel_launch(void* const* d_in, const int* in_sizes, int n_in, void* d_out,
                              int out_size, void* d_ws, size_t ws_size, hipStream_t stream) {
  (void)in_sizes; (void)n_in; (void)out_size; (void)ws_size;
  const float* x       = (const float*)d_in[0];
  const float* g_out   = (const float*)d_in[1];
  const float* dconv_w = (const float*)d_in[2];
  const float* dconv_b = (const float*)d_in[3];
  const float* p1_w    = (const float*)d_in[4];
  const float* p1_b    = (const float*)d_in[5];
  const float* p1_ain  = (const float*)d_in[6];
  const float* p1_aout = (const float*)d_in[7];
  const float* p2_w    = (const float*)d_in[8];
  const float* p2_b    = (const float*)d_in[9];
  const float* p2_ain  = (const float*)d_in[10];
  const float* p2_aout = (const float*)d_in[11];
  const float* out_w   = (const float*)d_in[12];
  const float* out_b   = (const float*)d_in[13];
  const float* out_ain = (const float*)d_in[14];
  const float* out_aout= (const float*)d_in[15];

  // Workspace (peak ~170.6 MB < R1-proven 192.3 MB).
  char* ws = (char*)d_ws;
  float* ain1  = (float*)(ws + 0);
  float* aout1 = (float*)(ws + 196608);
  float* ain2  = (float*)(ws + 786432);
  float* aout2 = (float*)(ws + 1376256);
  float* ain3  = (float*)(ws + 1572864);
  float* aout3 = (float*)(ws + 1835008);
  float* Atab2 = (float*)(ws + 2360320);   // 2 tables * 576*544*4 = 2,506,752 B
  double* win  = (double*)(ws + 4867072);  // 8,192 B
  char*  arena = ws + 4875264;
  // arena slots (fp32), lifetime-disjoint:
  float* weff1 = (float*)(arena + 0);           // 25,165,824  [weff1 .. chunk loop]
  float* weff2 = (float*)(arena + 25165824);    // 25,165,824  [weff2 .. chunk loop]
  float* h1c   = (float*)(arena + 50331648);    // 25,165,824  [per-chunk scratch]
  float* weff3 = (float*)(arena + 75497472);    // 18,874,368  [weff3 .. GEMM3]
  float* h0    = (float*)(arena + 94371840);    // 33,554,432  [dconv .. chunk loop]
  float* h2    = (float*)(arena + 127926272);   // 33,554,432  [chunk loop .. GEMM3]
  float* mp    = (float*)(arena + 0);           // 71,303,168  [GEMM3 .. sprep]
  float* Sre   = (float*)(arena + 94371840);    // 35,651,584  [sprep .. gemm64s]
  float* Sim   = (float*)(arena + 130023424);   // 35,651,584  [sprep .. gemm64s]
  float* CD    = (float*)(arena + 0);           // 75,497,472  [gemm64s .. ola]

  lora_vec_k<<<1536, 256, 0, stream>>>(p1_ain, 6144, g_out, ain1);
  lora_vec_k<<<4608, 256, 0, stream>>>(p1_aout, 18432, g_out, aout1);
  lora_vec_k<<<4608, 256, 0, stream>>>(p2_ain, 18432, g_out, ain2);
  lora_vec_k<<<1536, 256, 0, stream>>>(p2_aout, 6144, g_out, aout2);
  lora_vec_k<<<2048, 256, 0, stream>>>(out_ain, 8192, g_out, ain3);
  lora_vec_k<<<4104, 256, 0, stream>>>(out_aout, 16416, g_out, aout3);
  atab2_k<<<2448, 256, 0, stream>>>(Atab2, win);
  dconv_k<<<dim3(32, 8, 8), 256, 0, stream>>>(x, dconv_w, dconv_b, h0);
  weff_k<<<dim3(3072, 1, 8), 256, 0, stream>>>(p1_w, ain1, aout1, weff1, 1536, 1536, 512, 12);
  weff_k<<<dim3(3072, 1, 8), 256, 0, stream>>>(p2_w, ain2, aout2, weff2, 512, 512, 1536, 12);

  // layers 1+2 in 4 time-chunks of 512 through h1c
  for (int c = 0; c < 4; c++) {
    const float* h0c = h0 + (size_t)c * 512 * 512;
    float* h2c = h2 + (size_t)c * 512 * 512;
    gemm32<true><<<dim3(24, 8, 8), 256, 0, stream>>>(
        weff1, (size_t)1536 * 512, h0c, (size_t)2048 * 512, p1_b, 1536,
        h1c, (size_t)512 * 1536, 1536, 1536, 512);
    gemm32<true><<<dim3(8, 8, 8), 256, 0, stream>>>(
        weff2, (size_t)512 * 1536, h1c, (size_t)512 * 1536, p2_b, 512,
        h2c, (size_t)2048 * 512, 512, 512, 1536);
  }

  weff_k<<<dim3(2304, 1, 8), 256, 0, stream>>>(out_w, ain3, aout3, weff3, 1026, 1152, 512, 16);
  gemm32<false><<<dim3(18, 32, 8), 256, 0, stream>>>(
      weff3, (size_t)1152 * 512, h2, (size_t)2048 * 512, out_b, 1026,
      mp, (size_t)2048 * SPADK, SPADK, SPADK, 512);
  sprep2_k<<<34816, 256, 0, stream>>>(mp, Sre, Sim);
  // cos-part -> CD[:, :, 0:576], sin-part -> CD[:, :, 576:1152]
  gemm64s<<<dim3(9, 32, 8), 256, 0, stream>>>(
      Atab2, Sre, (size_t)2048 * ATK, CD, (size_t)2048 * 1152, 1152, ATK);
  gemm64s<<<dim3(9, 32, 8), 256, 0, stream>>>(
      Atab2 + ATSZ, Sim, (size_t)2048 * ATK, CD + 576, (size_t)2048 * 1152, 1152, ATK);
  ola_k<<<16384, 256, 0, stream>>>(CD, win, (float*)d_out);
}

// Round 2
// 1771.166 us; speedup vs baseline: 1.5955x; 1.4026x over previous
//
#include <hip/hip_runtime.h>

#define L_SZ 2048
#define DIM_SZ 512
#define SPADK 1088   // mp logits row: 513 mag + 513 phase + 62 pad
#define ATK 544      // symmetric iSTFT GEMM K: 513 padded to 17*32
#define ATM 576      // symmetric iSTFT GEMM M: 513 padded to 9*64
#define ATSZ (ATM * ATK)   // 313344 elems per table

// ---------------- per-batch LoRA factor GEMVs: out[b*rows + r] = dot(mat[r], g[b]) ----
__global__ __launch_bounds__(256) void lora_vec_k(const float* __restrict__ mat, int rows,
                                                  const float* __restrict__ g,
                                                  float* __restrict__ out) {
  __shared__ float gs[2048];
  int tid = threadIdx.x;
#pragma unroll
  for (int i = 0; i < 8; i++) gs[i * 256 + tid] = g[i * 256 + tid];
  __syncthreads();
  int row = blockIdx.x * 4 + (tid >> 6);
  if (row >= rows) return;
  int lane = tid & 63;
  float4 mv = *(const float4*)(mat + (size_t)row * 256 + lane * 4);
  float p[8];
#pragma unroll
  for (int b = 0; b < 8; b++) {
    const float* gb = gs + b * 256 + lane * 4;
    p[b] = mv.x * gb[0] + mv.y * gb[1] + mv.z * gb[2] + mv.w * gb[3];
  }
#pragma unroll
  for (int b = 0; b < 8; b++) {
    float v = p[b];
#pragma unroll
    for (int off = 32; off > 0; off >>= 1) v += __shfl_down(v, off, 64);
    if (lane == 0) out[(size_t)b * rows + row] = v;
  }
}

// ------- W_eff[b][m][k] = W[m][k] + sum_r aout[b][r*M+m] * ain[b][k*R+r]  (fp32) -------
__global__ __launch_bounds__(256) void weff_k(const float* __restrict__ W,
                                              const float* __restrict__ ain,
                                              const float* __restrict__ aout,
                                              float* __restrict__ out, int M, int Mpad,
                                              int K, int R) {
  int b = blockIdx.z;
  size_t flat = (size_t)blockIdx.x * 256 + threadIdx.x;  // over Mpad*K (exact multiple)
  int m = (int)(flat / K), k = (int)(flat % K);
  float v = 0.f;
  if (m < M) {
    v = W[(size_t)m * K + k];
    const float* ai = ain + ((size_t)b * K + k) * R;
    const float* ao = aout + (size_t)b * M * R + m;
    for (int r = 0; r < R; r++) v += ai[r] * ao[(size_t)r * M];
  }
  out[((size_t)b * Mpad + m) * K + k] = v;
}

// -------- causal depthwise conv: h0[b][t][c] = sum_k w[c][k] * x[b][c][t-k]  (fp32) ----
__global__ __launch_bounds__(256) void dconv_k(const float* __restrict__ x,
                                               const float* __restrict__ w,
                                               const float* __restrict__ bias,
                                               float* __restrict__ h0) {
  const int t0 = blockIdx.x * 64;
  const int c0 = blockIdx.y * 64;
  const int b = blockIdx.z;
  const int tid = threadIdx.x;
  __shared__ float xs[64 * 68];
  const float* xb = x + ((size_t)b * DIM_SZ + c0) * L_SZ;
#pragma unroll
  for (int i = 0; i < 17; i++) {
    int flat = i * 256 + tid;  // 0..4351 = 64*68
    int c = flat / 68, tt = flat % 68;
    int t = t0 - 4 + tt;
    xs[c * 68 + tt] = (t >= 0) ? xb[(size_t)c * L_SZ + t] : 0.0f;
  }
  __syncthreads();
  int c = tid & 63;
  int tb = (tid >> 6) * 16;
  float wl[5];
#pragma unroll
  for (int k = 0; k < 5; k++) wl[k] = w[(c0 + c) * 5 + k];
  float bl = bias[c0 + c];
  float* o = h0 + ((size_t)b * L_SZ + t0 + tb) * DIM_SZ + c0 + c;
#pragma unroll
  for (int j = 0; j < 16; j++) {
    int t = tb + j;
    float acc = bl;
#pragma unroll
    for (int k = 0; k < 5; k++) acc += wl[k] * xs[c * 68 + t + 4 - k];
    o[(size_t)j * DIM_SZ] = acc;
  }
}

// ---- symmetric istft basis tables (window + sideband weights folded), fp32; + win ----
// table 0: Ac[n][k] = wn[n] * wk_k * cos(2*pi*k*n/1024)   (n,k in 0..512, rest 0)
// table 1: As[n][k] = wn[n] * 2    * sin(2*pi*k*n/1024)
__global__ __launch_bounds__(256) void atab2_k(float* __restrict__ A,
                                               double* __restrict__ win) {
  int flat = blockIdx.x * 256 + threadIdx.x;  // over 2*576*544 = 626688
  int table = flat / ATSZ;
  int rem = flat - table * ATSZ;
  int n = rem / ATK, k = rem % ATK;
  const double W = 6.283185307179586476925287 / 1024.0;
  float val = 0.f;
  if (n <= 512 && k <= 512) {
    double wn = 0.5 * (1.0 - cos(W * (double)n));
    int mm = (k * n) & 1023;
    if (table == 0) {
      double wk = (k == 0 || k == 512) ? 1.0 : 2.0;
      val = (float)(wn * wk * cos(W * (double)mm));
    } else {
      val = (float)(wn * 2.0 * sin(W * (double)mm));
    }
  }
  A[flat] = val;
  if (flat < 1024) win[flat] = 0.5 * (1.0 - cos(W * (double)flat));
}

// ------- S prep: read fp32 (m,p) logits row, write Sre = mag*cos(p), Sim = mag*sin(p) --
__global__ __launch_bounds__(256) void sprep2_k(const float* __restrict__ mp,
                                                float* __restrict__ Sre,
                                                float* __restrict__ Sim) {
  size_t flat = (size_t)blockIdx.x * 256 + threadIdx.x;  // over 8*2048*544
  size_t row = flat / ATK;
  int k = (int)(flat % ATK);
  float re = 0.f, im = 0.f;
  if (k < 513) {
    const float* r = mp + row * SPADK;
    float m = r[k], p = r[513 + k];
    float mag = fminf(expf(m), 100.0f);
    re = mag * cosf(p);
    im = mag * sinf(p);
  }
  Sre[row * ATK + k] = re;
  Sim[row * ATK + k] = im;
}

// ---- fp32 GEMM, TRANSPOSED (K-major) LDS tiles so the inner loop is ds_read_b128:
//      C[b][t][m] = act( sum_k A[b][m][k] * B[b][t][k] + bias[m] )
// LDS stride 68: inner b128 reads are 2-way bank-aliased (free), staging scatter 4-way.
template <bool GELU>
__global__ __launch_bounds__(256) void gemm32t(const float* __restrict__ A, size_t a_bs,
                                               const float* __restrict__ Bm, size_t b_bs,
                                               const float* __restrict__ bias, int Mb,
                                               float* __restrict__ C, size_t c_bs, int ldc,
                                               int Mst, int K) {
  const int b = blockIdx.z;
  const int m0 = blockIdx.x * 64;
  const int t0 = blockIdx.y * 64;
  const int tid = threadIdx.x;
  __shared__ float As[32][68];   // [kk][m]
  __shared__ float Bs[32][68];   // [kk][t]
  const float* Ab = A + (size_t)b * a_bs + (size_t)m0 * K;
  const float* Bb = Bm + (size_t)b * b_bs + (size_t)t0 * K;
  const int tm = tid & 15;   // m-subtile
  const int tt = tid >> 4;   // t-subtile
  float acc[4][4] = {};
  for (int kt = 0; kt < K; kt += 32) {
#pragma unroll
    for (int i = 0; i < 2; i++) {
      int ch = i * 256 + tid;            // 0..511
      int row = ch >> 3, kc = (ch & 7) * 4;
      float4 a4 = *(const float4*)(Ab + (size_t)row * K + kt + kc);
      float4 b4 = *(const float4*)(Bb + (size_t)row * K + kt + kc);
      As[kc + 0][row] = a4.x; As[kc + 1][row] = a4.y;
      As[kc + 2][row] = a4.z; As[kc + 3][row] = a4.w;
      Bs[kc + 0][row] = b4.x; Bs[kc + 1][row] = b4.y;
      Bs[kc + 2][row] = b4.z; Bs[kc + 3][row] = b4.w;
    }
    __syncthreads();
#pragma unroll 8
    for (int kk = 0; kk < 32; kk++) {
      float4 am = *(const float4*)(&As[kk][tm * 4]);
      float4 bv = *(const float4*)(&Bs[kk][tt * 4]);
      const float* ap = &am.x;
      const float* bp = &bv.x;
#pragma unroll
      for (int i = 0; i < 4; i++)
#pragma unroll
        for (int j = 0; j < 4; j++) acc[i][j] += ap[i] * bp[j];
    }
    __syncthreads();
  }
  if (m0 + tm * 4 >= Mst) return;  // clip padded A rows
#pragma unroll
  for (int j = 0; j < 4; j++) {
    float4 v4;
    float* vp = &v4.x;
#pragma unroll
    for (int i = 0; i < 4; i++) {
      float v = acc[i][j];
      int m = m0 + tm * 4 + i;
      if (bias != nullptr && m < Mb) v += bias[m];
      if (GELU) v = 0.5f * v * (1.0f + erff(v * 0.70710678118654752f));
      vp[i] = v;
    }
    *(float4*)(C + (size_t)b * c_bs + (size_t)(t0 + tt * 4 + j) * ldc + m0 + tm * 4) = v4;
  }
}

// ------- overlap-add + env normalize + crop, with symmetric frame reconstruction:
//   frame[tau][n] = C[tau][n] - D[tau][n]            (n <= 512)
//                 = C[tau][1024-n] + D[tau][1024-n]  (n >= 513)
__global__ __launch_bounds__(256) void ola_k(const float* __restrict__ CD,
                                             const double* __restrict__ win,
                                             float* __restrict__ out) {
  size_t flat = (size_t)blockIdx.x * 256 + threadIdx.x;  // over 8*524288
  int b = (int)(flat >> 19);
  int t = (int)(flat & 524287);
  int g = t + 384;  // PAD
  int r = g & 255, q4 = g >> 8;
  double acc = 0.0, env = 0.0;
#pragma unroll
  for (int q = 0; q < 4; q++) {
    int tau = q4 - q;
    int n = r + 256 * q;
    if (tau >= 0 && tau < 2048) {
      double w = win[n];
      int np = (n <= 512) ? n : 1024 - n;
      double sgn = (n <= 512) ? -1.0 : 1.0;
      const float* base = CD + ((size_t)b * 2048 + tau) * 1152 + np;
      acc += (double)base[0] + sgn * (double)base[576];
      env = fma(w, w, env);
    }
  }
  out[flat] = (float)(acc / (env * 1024.0));
}

extern "C" void kernel_launch(void* const* d_in, const int* in_sizes, int n_in, void* d_out,
                              int out_size, void* d_ws, size_t ws_size, hipStream_t stream) {
  (void)in_sizes; (void)n_in; (void)out_size; (void)ws_size;
  const float* x       = (const float*)d_in[0];
  const float* g_out   = (const float*)d_in[1];
  const float* dconv_w = (const float*)d_in[2];
  const float* dconv_b = (const float*)d_in[3];
  const float* p1_w    = (const float*)d_in[4];
  const float* p1_b    = (const float*)d_in[5];
  const float* p1_ain  = (const float*)d_in[6];
  const float* p1_aout = (const float*)d_in[7];
  const float* p2_w    = (const float*)d_in[8];
  const float* p2_b    = (const float*)d_in[9];
  const float* p2_ain  = (const float*)d_in[10];
  const float* p2_aout = (const float*)d_in[11];
  const float* out_w   = (const float*)d_in[12];
  const float* out_b   = (const float*)d_in[13];
  const float* out_ain = (const float*)d_in[14];
  const float* out_aout= (const float*)d_in[15];

  // Workspace. Front tables + arena with time-shared slots; peak 164.3 MB < proven 192.3.
  char* ws = (char*)d_ws;
  float* ain1  = (float*)(ws + 0);
  float* aout1 = (float*)(ws + 196608);
  float* ain2  = (float*)(ws + 786432);
  float* aout2 = (float*)(ws + 1376256);
  float* ain3  = (float*)(ws + 1572864);
  float* aout3 = (float*)(ws + 1835008);
  float* Atab2 = (float*)(ws + 2360320);   // 2 tables * 576*544*4 = 2,506,752 B
  double* win  = (double*)(ws + 4867072);  // 8,192 B
  char*  arena = ws + 4875264;
  // arena slots (fp32), time-shared (stream order guarantees disjoint lifetimes):
  //   slot B [0 .. 100,663,296)          : h1  -> mp -> CD
  //   slot A [100,663,296 .. 134,217,728): h0  -> h2
  //   slot W [134,217,728 .. 159,383,552): weff1 -> weff2 -> weff3
  //   Sre [75,497,472 .. 111,149,056), Sim [111,149,056 .. 146,800,640)
  //     (written by sprep after GEMM3, when mp tail/h2/weff3 regions they overlap are dead;
  //      CD [0 .. 75,497,472) is disjoint from Sre/Sim during the iSTFT GEMMs)
  float* h1    = (float*)(arena + 0);
  float* mp    = (float*)(arena + 0);
  float* CD    = (float*)(arena + 0);
  float* h0    = (float*)(arena + 100663296);
  float* h2    = (float*)(arena + 100663296);
  float* weff1 = (float*)(arena + 134217728);
  float* weff2 = (float*)(arena + 134217728);
  float* weff3 = (float*)(arena + 134217728);
  float* Sre   = (float*)(arena + 75497472);
  float* Sim   = (float*)(arena + 111149056);

  lora_vec_k<<<1536, 256, 0, stream>>>(p1_ain, 6144, g_out, ain1);
  lora_vec_k<<<4608, 256, 0, stream>>>(p1_aout, 18432, g_out, aout1);
  lora_vec_k<<<4608, 256, 0, stream>>>(p2_ain, 18432, g_out, ain2);
  lora_vec_k<<<1536, 256, 0, stream>>>(p2_aout, 6144, g_out, aout2);
  lora_vec_k<<<2048, 256, 0, stream>>>(out_ain, 8192, g_out, ain3);
  lora_vec_k<<<4104, 256, 0, stream>>>(out_aout, 16416, g_out, aout3);
  atab2_k<<<2448, 256, 0, stream>>>(Atab2, win);
  dconv_k<<<dim3(32, 8, 8), 256, 0, stream>>>(x, dconv_w, dconv_b, h0);

  // layer 1 (full T): h1[b][t][0..1536) = gelu(weff1 . h0 + b1)
  weff_k<<<dim3(3072, 1, 8), 256, 0, stream>>>(p1_w, ain1, aout1, weff1, 1536, 1536, 512, 12);
  gemm32t<true><<<dim3(24, 32, 8), 256, 0, stream>>>(
      weff1, (size_t)1536 * 512, h0, (size_t)2048 * 512, p1_b, 1536,
      h1, (size_t)2048 * 1536, 1536, 1536, 512);

  // layer 2 (full T): h2 = gelu(weff2 . h1 + b2)   [weff2 reuses weff1's slot]
  weff_k<<<dim3(3072, 1, 8), 256, 0, stream>>>(p2_w, ain2, aout2, weff2, 512, 512, 1536, 12);
  gemm32t<true><<<dim3(8, 32, 8), 256, 0, stream>>>(
      weff2, (size_t)512 * 1536, h1, (size_t)2048 * 1536, p2_b, 512,
      h2, (size_t)2048 * 512, 512, 512, 1536);

  // output projection: mp = weff3 . h2 + out_b     [mp reuses h1's slot]
  weff_k<<<dim3(2304, 1, 8), 256, 0, stream>>>(out_w, ain3, aout3, weff3, 1026, 1152, 512, 16);
  gemm32t<false><<<dim3(18, 32, 8), 256, 0, stream>>>(
      weff3, (size_t)1152 * 512, h2, (size_t)2048 * 512, out_b, 1026,
      mp, (size_t)2048 * SPADK, SPADK, SPADK, 512);

  sprep2_k<<<34816, 256, 0, stream>>>(mp, Sre, Sim);
  // cos-part -> CD[:, :, 0:576], sin-part -> CD[:, :, 576:1152]   (fp32 accum; error
  // model: sqrt(544)*eps*|acc|~5e-5 in frames, /1536 at OLA -> ~3e-8 at output)
  gemm32t<false><<<dim3(9, 32, 8), 256, 0, stream>>>(
      Atab2, (size_t)0, Sre, (size_t)2048 * ATK, nullptr, 0,
      CD, (size_t)2048 * 1152, 1152, 1152, ATK);
  gemm32t<false><<<dim3(9, 32, 8), 256, 0, stream>>>(
      Atab2 + ATSZ, (size_t)0, Sim, (size_t)2048 * ATK, nullptr, 0,
      CD + 576, (size_t)2048 * 1152, 1152, 1152, ATK);
  ola_k<<<16384, 256, 0, stream>>>(CD, win, (float*)d_out);
}

// Round 3
// 1707.980 us; speedup vs baseline: 1.6545x; 1.0370x over previous
//
#include <hip/hip_runtime.h>

#define L_SZ 2048
#define DIM_SZ 512
#define SPADK 1088   // mp logits row: 513 mag + 513 phase + 62 pad
#define ATK 544      // symmetric iSTFT GEMM K: 513 padded to 17*32
#define ATM 576      // symmetric iSTFT GEMM M: 513 padded to 9*64
#define ATSZ (ATM * ATK)   // 313344 elems per table

// ---------------- per-batch LoRA factor GEMVs: out[b*rows + r] = dot(mat[r], g[b]) ----
__global__ __launch_bounds__(256) void lora_vec_k(const float* __restrict__ mat, int rows,
                                                  const float* __restrict__ g,
                                                  float* __restrict__ out) {
  __shared__ float gs[2048];
  int tid = threadIdx.x;
#pragma unroll
  for (int i = 0; i < 8; i++) gs[i * 256 + tid] = g[i * 256 + tid];
  __syncthreads();
  int row = blockIdx.x * 4 + (tid >> 6);
  if (row >= rows) return;
  int lane = tid & 63;
  float4 mv = *(const float4*)(mat + (size_t)row * 256 + lane * 4);
  float p[8];
#pragma unroll
  for (int b = 0; b < 8; b++) {
    const float* gb = gs + b * 256 + lane * 4;
    p[b] = mv.x * gb[0] + mv.y * gb[1] + mv.z * gb[2] + mv.w * gb[3];
  }
#pragma unroll
  for (int b = 0; b < 8; b++) {
    float v = p[b];
#pragma unroll
    for (int off = 32; off > 0; off >>= 1) v += __shfl_down(v, off, 64);
    if (lane == 0) out[(size_t)b * rows + row] = v;
  }
}

// ------- W_eff[b][m][k] = W[m][k] + sum_r aout[b][r*M+m] * ain[b][k*R+r]  (fp32) -------
__global__ __launch_bounds__(256) void weff_k(const float* __restrict__ W,
                                              const float* __restrict__ ain,
                                              const float* __restrict__ aout,
                                              float* __restrict__ out, int M, int Mpad,
                                              int K, int R) {
  int b = blockIdx.z;
  size_t flat = (size_t)blockIdx.x * 256 + threadIdx.x;  // over Mpad*K (exact multiple)
  int m = (int)(flat / K), k = (int)(flat % K);
  float v = 0.f;
  if (m < M) {
    v = W[(size_t)m * K + k];
    const float* ai = ain + ((size_t)b * K + k) * R;
    const float* ao = aout + (size_t)b * M * R + m;
    for (int r = 0; r < R; r++) v += ai[r] * ao[(size_t)r * M];
  }
  out[((size_t)b * Mpad + m) * K + k] = v;
}

// -------- causal depthwise conv: h0[b][t][c] = sum_k w[c][k] * x[b][c][t-k]  (fp32) ----
__global__ __launch_bounds__(256) void dconv_k(const float* __restrict__ x,
                                               const float* __restrict__ w,
                                               const float* __restrict__ bias,
                                               float* __restrict__ h0) {
  const int t0 = blockIdx.x * 64;
  const int c0 = blockIdx.y * 64;
  const int b = blockIdx.z;
  const int tid = threadIdx.x;
  __shared__ float xs[64 * 68];
  const float* xb = x + ((size_t)b * DIM_SZ + c0) * L_SZ;
#pragma unroll
  for (int i = 0; i < 17; i++) {
    int flat = i * 256 + tid;  // 0..4351 = 64*68
    int c = flat / 68, tt = flat % 68;
    int t = t0 - 4 + tt;
    xs[c * 68 + tt] = (t >= 0) ? xb[(size_t)c * L_SZ + t] : 0.0f;
  }
  __syncthreads();
  int c = tid & 63;
  int tb = (tid >> 6) * 16;
  float wl[5];
#pragma unroll
  for (int k = 0; k < 5; k++) wl[k] = w[(c0 + c) * 5 + k];
  float bl = bias[c0 + c];
  float* o = h0 + ((size_t)b * L_SZ + t0 + tb) * DIM_SZ + c0 + c;
#pragma unroll
  for (int j = 0; j < 16; j++) {
    int t = tb + j;
    float acc = bl;
#pragma unroll
    for (int k = 0; k < 5; k++) acc += wl[k] * xs[c * 68 + t + 4 - k];
    o[(size_t)j * DIM_SZ] = acc;
  }
}

// ---- symmetric istft basis tables (window + sideband weights folded), fp32; + win ----
__global__ __launch_bounds__(256) void atab2_k(float* __restrict__ A,
                                               double* __restrict__ win) {
  int flat = blockIdx.x * 256 + threadIdx.x;  // over 2*576*544 = 626688
  int table = flat / ATSZ;
  int rem = flat - table * ATSZ;
  int n = rem / ATK, k = rem % ATK;
  const double W = 6.283185307179586476925287 / 1024.0;
  float val = 0.f;
  if (n <= 512 && k <= 512) {
    double wn = 0.5 * (1.0 - cos(W * (double)n));
    int mm = (k * n) & 1023;
    if (table == 0) {
      double wk = (k == 0 || k == 512) ? 1.0 : 2.0;
      val = (float)(wn * wk * cos(W * (double)mm));
    } else {
      val = (float)(wn * 2.0 * sin(W * (double)mm));
    }
  }
  A[flat] = val;
  if (flat < 1024) win[flat] = 0.5 * (1.0 - cos(W * (double)flat));
}

// ------- S prep: read fp32 (m,p) logits row, write Sre = mag*cos(p), Sim = mag*sin(p) --
__global__ __launch_bounds__(256) void sprep2_k(const float* __restrict__ mp,
                                                float* __restrict__ Sre,
                                                float* __restrict__ Sim) {
  size_t flat = (size_t)blockIdx.x * 256 + threadIdx.x;  // over 8*2048*544
  size_t row = flat / ATK;
  int k = (int)(flat % ATK);
  float re = 0.f, im = 0.f;
  if (k < 513) {
    const float* r = mp + row * SPADK;
    float m = r[k], p = r[513 + k];
    float mag = fminf(expf(m), 100.0f);
    re = mag * cosf(p);
    im = mag * sinf(p);
  }
  Sre[row * ATK + k] = re;
  Sim[row * ATK + k] = im;
}

// ---- fp32 GEMM, 64x64 tile, K-major LDS (used for the iSTFT basis GEMMs, M=576) ----
template <bool GELU>
__global__ __launch_bounds__(256) void gemm32t(const float* __restrict__ A, size_t a_bs,
                                               const float* __restrict__ Bm, size_t b_bs,
                                               const float* __restrict__ bias, int Mb,
                                               float* __restrict__ C, size_t c_bs, int ldc,
                                               int Mst, int K) {
  const int b = blockIdx.z;
  const int m0 = blockIdx.x * 64;
  const int t0 = blockIdx.y * 64;
  const int tid = threadIdx.x;
  __shared__ float As[32][68];   // [kk][m]
  __shared__ float Bs[32][68];   // [kk][t]
  const float* Ab = A + (size_t)b * a_bs + (size_t)m0 * K;
  const float* Bb = Bm + (size_t)b * b_bs + (size_t)t0 * K;
  const int tm = tid & 15;   // m-subtile
  const int tt = tid >> 4;   // t-subtile
  float acc[4][4] = {};
  for (int kt = 0; kt < K; kt += 32) {
#pragma unroll
    for (int i = 0; i < 2; i++) {
      int ch = i * 256 + tid;            // 0..511
      int row = ch >> 3, kc = (ch & 7) * 4;
      float4 a4 = *(const float4*)(Ab + (size_t)row * K + kt + kc);
      float4 b4 = *(const float4*)(Bb + (size_t)row * K + kt + kc);
      As[kc + 0][row] = a4.x; As[kc + 1][row] = a4.y;
      As[kc + 2][row] = a4.z; As[kc + 3][row] = a4.w;
      Bs[kc + 0][row] = b4.x; Bs[kc + 1][row] = b4.y;
      Bs[kc + 2][row] = b4.z; Bs[kc + 3][row] = b4.w;
    }
    __syncthreads();
#pragma unroll 8
    for (int kk = 0; kk < 32; kk++) {
      float4 am = *(const float4*)(&As[kk][tm * 4]);
      float4 bv = *(const float4*)(&Bs[kk][tt * 4]);
      const float* ap = &am.x;
      const float* bp = &bv.x;
#pragma unroll
      for (int i = 0; i < 4; i++)
#pragma unroll
        for (int j = 0; j < 4; j++) acc[i][j] += ap[i] * bp[j];
    }
    __syncthreads();
  }
  if (m0 + tm * 4 >= Mst) return;  // clip padded A rows
#pragma unroll
  for (int j = 0; j < 4; j++) {
    float4 v4;
    float* vp = &v4.x;
#pragma unroll
    for (int i = 0; i < 4; i++) {
      float v = acc[i][j];
      int m = m0 + tm * 4 + i;
      if (bias != nullptr && m < Mb) v += bias[m];
      if (GELU) v = 0.5f * v * (1.0f + erff(v * 0.70710678118654752f));
      vp[i] = v;
    }
    *(float4*)(C + (size_t)b * c_bs + (size_t)(t0 + tt * 4 + j) * ldc + m0 + tm * 4) = v4;
  }
}

// ---- fp32 GEMM, 128x128 tile, 8x8 acc/thread, K-major LDS; for the layer GEMMs ----
//      C[b][t][m] = act( sum_k A[b][m][k] * B[b][t][k] + bias[m] )
// Fragment split: thread (tm,tt) owns m in {m0+tm*4..+3} u {m0+64+tm*4..+3}, t likewise.
// A-frag reads: 16 lanes stride 4 floats span 64 floats = 2 bank wraps -> 2-way (free).
// B-frag reads: 16-lane same-address broadcast (free).
template <bool GELU>
__global__ __launch_bounds__(256) void gemm128(const float* __restrict__ A, size_t a_bs,
                                               const float* __restrict__ Bm, size_t b_bs,
                                               const float* __restrict__ bias, int Mb,
                                               float* __restrict__ C, size_t c_bs, int ldc,
                                               int Mst, int K) {
  const int b = blockIdx.z;
  const int m0 = blockIdx.x * 128;
  const int t0 = blockIdx.y * 128;
  const int tid = threadIdx.x;
  __shared__ float As[32][132];   // [kk][m]
  __shared__ float Bs[32][132];   // [kk][t]
  const float* Ab = A + (size_t)b * a_bs + (size_t)m0 * K;
  const float* Bb = Bm + (size_t)b * b_bs + (size_t)t0 * K;
  const int tm = tid & 15;
  const int tt = tid >> 4;
  float acc[8][8] = {};
  for (int kt = 0; kt < K; kt += 32) {
#pragma unroll
    for (int i = 0; i < 4; i++) {
      int ch = i * 256 + tid;            // 0..1023 over 128 rows x 8 float4
      int row = ch >> 3, kc = (ch & 7) * 4;
      float4 a4 = *(const float4*)(Ab + (size_t)row * K + kt + kc);
      float4 b4 = *(const float4*)(Bb + (size_t)row * K + kt + kc);
      As[kc + 0][row] = a4.x; As[kc + 1][row] = a4.y;
      As[kc + 2][row] = a4.z; As[kc + 3][row] = a4.w;
      Bs[kc + 0][row] = b4.x; Bs[kc + 1][row] = b4.y;
      Bs[kc + 2][row] = b4.z; Bs[kc + 3][row] = b4.w;
    }
    __syncthreads();
#pragma unroll 8
    for (int kk = 0; kk < 32; kk++) {
      float4 a0 = *(const float4*)(&As[kk][tm * 4]);
      float4 a1 = *(const float4*)(&As[kk][64 + tm * 4]);
      float4 b0 = *(const float4*)(&Bs[kk][tt * 4]);
      float4 b1 = *(const float4*)(&Bs[kk][64 + tt * 4]);
      float am[8] = {a0.x, a0.y, a0.z, a0.w, a1.x, a1.y, a1.z, a1.w};
      float bv[8] = {b0.x, b0.y, b0.z, b0.w, b1.x, b1.y, b1.z, b1.w};
#pragma unroll
      for (int i = 0; i < 8; i++)
#pragma unroll
        for (int j = 0; j < 8; j++) acc[i][j] += am[i] * bv[j];
    }
    __syncthreads();
  }
#pragma unroll
  for (int jh = 0; jh < 2; jh++) {
#pragma unroll
    for (int j = 0; j < 4; j++) {
      int t = t0 + jh * 64 + tt * 4 + j;
#pragma unroll
      for (int ih = 0; ih < 2; ih++) {
        int m = m0 + ih * 64 + tm * 4;
        if (m >= Mst) continue;  // clip padded A rows (Mst multiple of 4)
        float4 v4;
        float* vp = &v4.x;
#pragma unroll
        for (int i = 0; i < 4; i++) {
          float v = acc[ih * 4 + i][jh * 4 + j];
          if (bias != nullptr && m + i < Mb) v += bias[m + i];
          if (GELU) v = 0.5f * v * (1.0f + erff(v * 0.70710678118654752f));
          vp[i] = v;
        }
        *(float4*)(C + (size_t)b * c_bs + (size_t)t * ldc + m) = v4;
      }
    }
  }
}

// ------- overlap-add + env normalize + crop, with symmetric frame reconstruction:
//   frame[tau][n] = C[tau][n] - D[tau][n]            (n <= 512)
//                 = C[tau][1024-n] + D[tau][1024-n]  (n >= 513)
__global__ __launch_bounds__(256) void ola_k(const float* __restrict__ CD,
                                             const double* __restrict__ win,
                                             float* __restrict__ out) {
  size_t flat = (size_t)blockIdx.x * 256 + threadIdx.x;  // over 8*524288
  int b = (int)(flat >> 19);
  int t = (int)(flat & 524287);
  int g = t + 384;  // PAD
  int r = g & 255, q4 = g >> 8;
  double acc = 0.0, env = 0.0;
#pragma unroll
  for (int q = 0; q < 4; q++) {
    int tau = q4 - q;
    int n = r + 256 * q;
    if (tau >= 0 && tau < 2048) {
      double w = win[n];
      int np = (n <= 512) ? n : 1024 - n;
      double sgn = (n <= 512) ? -1.0 : 1.0;
      const float* base = CD + ((size_t)b * 2048 + tau) * 1152 + np;
      acc += (double)base[0] + sgn * (double)base[576];
      env = fma(w, w, env);
    }
  }
  out[flat] = (float)(acc / (env * 1024.0));
}

extern "C" void kernel_launch(void* const* d_in, const int* in_sizes, int n_in, void* d_out,
                              int out_size, void* d_ws, size_t ws_size, hipStream_t stream) {
  (void)in_sizes; (void)n_in; (void)out_size; (void)ws_size;
  const float* x       = (const float*)d_in[0];
  const float* g_out   = (const float*)d_in[1];
  const float* dconv_w = (const float*)d_in[2];
  const float* dconv_b = (const float*)d_in[3];
  const float* p1_w    = (const float*)d_in[4];
  const float* p1_b    = (const float*)d_in[5];
  const float* p1_ain  = (const float*)d_in[6];
  const float* p1_aout = (const float*)d_in[7];
  const float* p2_w    = (const float*)d_in[8];
  const float* p2_b    = (const float*)d_in[9];
  const float* p2_ain  = (const float*)d_in[10];
  const float* p2_aout = (const float*)d_in[11];
  const float* out_w   = (const float*)d_in[12];
  const float* out_b   = (const float*)d_in[13];
  const float* out_ain = (const float*)d_in[14];
  const float* out_aout= (const float*)d_in[15];

  // Workspace. Front tables + arena with time-shared slots; peak 164.3 MB < proven 192.3.
  char* ws = (char*)d_ws;
  float* ain1  = (float*)(ws + 0);
  float* aout1 = (float*)(ws + 196608);
  float* ain2  = (float*)(ws + 786432);
  float* aout2 = (float*)(ws + 1376256);
  float* ain3  = (float*)(ws + 1572864);
  float* aout3 = (float*)(ws + 1835008);
  float* Atab2 = (float*)(ws + 2360320);   // 2 tables * 576*544*4 = 2,506,752 B
  double* win  = (double*)(ws + 4867072);  // 8,192 B
  char*  arena = ws + 4875264;
  // arena slots (fp32), time-shared (stream order guarantees disjoint lifetimes):
  //   slot B [0 .. 100,663,296)          : h1  -> mp -> CD
  //   slot A [100,663,296 .. 134,217,728): h0  -> h2
  //   slot W [134,217,728 .. 159,383,552): weff1 -> weff2 -> weff3
  //   Sre [75,497,472 .. 111,149,056), Sim [111,149,056 .. 146,800,640)
  float* h1    = (float*)(arena + 0);
  float* mp    = (float*)(arena + 0);
  float* CD    = (float*)(arena + 0);
  float* h0    = (float*)(arena + 100663296);
  float* h2    = (float*)(arena + 100663296);
  float* weff1 = (float*)(arena + 134217728);
  float* weff2 = (float*)(arena + 134217728);
  float* weff3 = (float*)(arena + 134217728);
  float* Sre   = (float*)(arena + 75497472);
  float* Sim   = (float*)(arena + 111149056);

  lora_vec_k<<<1536, 256, 0, stream>>>(p1_ain, 6144, g_out, ain1);
  lora_vec_k<<<4608, 256, 0, stream>>>(p1_aout, 18432, g_out, aout1);
  lora_vec_k<<<4608, 256, 0, stream>>>(p2_ain, 18432, g_out, ain2);
  lora_vec_k<<<1536, 256, 0, stream>>>(p2_aout, 6144, g_out, aout2);
  lora_vec_k<<<2048, 256, 0, stream>>>(out_ain, 8192, g_out, ain3);
  lora_vec_k<<<4104, 256, 0, stream>>>(out_aout, 16416, g_out, aout3);
  atab2_k<<<2448, 256, 0, stream>>>(Atab2, win);
  dconv_k<<<dim3(32, 8, 8), 256, 0, stream>>>(x, dconv_w, dconv_b, h0);

  // layer 1 (full T): h1 = gelu(weff1 . h0 + b1)
  weff_k<<<dim3(3072, 1, 8), 256, 0, stream>>>(p1_w, ain1, aout1, weff1, 1536, 1536, 512, 12);
  gemm128<true><<<dim3(12, 16, 8), 256, 0, stream>>>(
      weff1, (size_t)1536 * 512, h0, (size_t)2048 * 512, p1_b, 1536,
      h1, (size_t)2048 * 1536, 1536, 1536, 512);

  // layer 2 (full T): h2 = gelu(weff2 . h1 + b2)   [weff2 reuses weff1's slot]
  weff_k<<<dim3(3072, 1, 8), 256, 0, stream>>>(p2_w, ain2, aout2, weff2, 512, 512, 1536, 12);
  gemm128<true><<<dim3(4, 16, 8), 256, 0, stream>>>(
      weff2, (size_t)512 * 1536, h1, (size_t)2048 * 1536, p2_b, 512,
      h2, (size_t)2048 * 512, 512, 512, 1536);

  // output projection: mp = weff3 . h2 + out_b     [mp reuses h1's slot]
  weff_k<<<dim3(2304, 1, 8), 256, 0, stream>>>(out_w, ain3, aout3, weff3, 1026, 1152, 512, 16);
  gemm128<false><<<dim3(9, 16, 8), 256, 0, stream>>>(
      weff3, (size_t)1152 * 512, h2, (size_t)2048 * 512, out_b, 1026,
      mp, (size_t)2048 * SPADK, SPADK, SPADK, 512);

  sprep2_k<<<34816, 256, 0, stream>>>(mp, Sre, Sim);
  // cos-part -> CD[:, :, 0:576], sin-part -> CD[:, :, 576:1152]
  gemm32t<false><<<dim3(9, 32, 8), 256, 0, stream>>>(
      Atab2, (size_t)0, Sre, (size_t)2048 * ATK, nullptr, 0,
      CD, (size_t)2048 * 1152, 1152, 1152, ATK);
  gemm32t<false><<<dim3(9, 32, 8), 256, 0, stream>>>(
      Atab2 + ATSZ, (size_t)0, Sim, (size_t)2048 * ATK, nullptr, 0,
      CD + 576, (size_t)2048 * 1152, 1152, 1152, ATK);
  ola_k<<<16384, 256, 0, stream>>>(CD, win, (float*)d_out);
}

// Round 4
// 1211.140 us; speedup vs baseline: 2.3333x; 1.4102x over previous
//
#include <hip/hip_runtime.h>

#define L_SZ 2048
#define DIM_SZ 512
#define SPADK 1088   // mp logits row: 513 mag + 513 phase + 62 pad
#define ATK 544      // symmetric iSTFT GEMM K: 513 padded to 17*32
#define ATM 576      // symmetric iSTFT GEMM M: 513 padded to 9*64
#define ATSZ (ATM * ATK)   // 313344 elems per table

typedef __attribute__((ext_vector_type(8))) short bfx8;
typedef __attribute__((ext_vector_type(4))) float f32x4;

// round-to-nearest-even fp32 -> bf16 helpers
__device__ __forceinline__ ushort f2bf(float v) {
  unsigned u = __float_as_uint(v);
  unsigned r = u + 0x7FFFu + ((u >> 16) & 1u);
  return (ushort)(r >> 16);
}
__device__ __forceinline__ float bfhi_f(float v) {
  unsigned u = __float_as_uint(v);
  unsigned r = (u + 0x7FFFu + ((u >> 16) & 1u)) & 0xFFFF0000u;
  return __uint_as_float(r);
}

// ---------------- per-batch LoRA factor GEMVs: out[b*rows + r] = dot(mat[r], g[b]) ----
__global__ __launch_bounds__(256) void lora_vec_k(const float* __restrict__ mat, int rows,
                                                  const float* __restrict__ g,
                                                  float* __restrict__ out) {
  __shared__ float gs[2048];
  int tid = threadIdx.x;
#pragma unroll
  for (int i = 0; i < 8; i++) gs[i * 256 + tid] = g[i * 256 + tid];
  __syncthreads();
  int row = blockIdx.x * 4 + (tid >> 6);
  if (row >= rows) return;
  int lane = tid & 63;
  float4 mv = *(const float4*)(mat + (size_t)row * 256 + lane * 4);
  float p[8];
#pragma unroll
  for (int b = 0; b < 8; b++) {
    const float* gb = gs + b * 256 + lane * 4;
    p[b] = mv.x * gb[0] + mv.y * gb[1] + mv.z * gb[2] + mv.w * gb[3];
  }
#pragma unroll
  for (int b = 0; b < 8; b++) {
    float v = p[b];
#pragma unroll
    for (int off = 32; off > 0; off >>= 1) v += __shfl_down(v, off, 64);
    if (lane == 0) out[(size_t)b * rows + row] = v;
  }
}

// --- W_eff[b][m][k] = W[m][k] + sum_r aout[b][r*M+m] * ain[b][k*R+r]; emit bf16 hi/lo --
__global__ __launch_bounds__(256) void weff_k(const float* __restrict__ W,
                                              const float* __restrict__ ain,
                                              const float* __restrict__ aout,
                                              ushort* __restrict__ oh,
                                              ushort* __restrict__ ol, int M, int Mpad,
                                              int K, int R) {
  int b = blockIdx.z;
  size_t flat = (size_t)blockIdx.x * 256 + threadIdx.x;  // over Mpad*K (exact multiple)
  int m = (int)(flat / K), k = (int)(flat % K);
  float v = 0.f;
  if (m < M) {
    v = W[(size_t)m * K + k];
    const float* ai = ain + ((size_t)b * K + k) * R;
    const float* ao = aout + (size_t)b * M * R + m;
    for (int r = 0; r < R; r++) v += ai[r] * ao[(size_t)r * M];
  }
  float hf = bfhi_f(v);
  size_t o = ((size_t)b * Mpad + m) * K + k;
  oh[o] = (ushort)(__float_as_uint(hf) >> 16);
  ol[o] = f2bf(v - hf);
}

// -- causal depthwise conv -> h0 as bf16 hi/lo: h0[b][t][c] = sum_k w[c][k]*x[b][c][t-k]
__global__ __launch_bounds__(256) void dconv_k(const float* __restrict__ x,
                                               const float* __restrict__ w,
                                               const float* __restrict__ bias,
                                               ushort* __restrict__ h0h,
                                               ushort* __restrict__ h0l) {
  const int t0 = blockIdx.x * 64;
  const int c0 = blockIdx.y * 64;
  const int b = blockIdx.z;
  const int tid = threadIdx.x;
  __shared__ float xs[64 * 68];
  const float* xb = x + ((size_t)b * DIM_SZ + c0) * L_SZ;
#pragma unroll
  for (int i = 0; i < 17; i++) {
    int flat = i * 256 + tid;  // 0..4351 = 64*68
    int c = flat / 68, tt = flat % 68;
    int t = t0 - 4 + tt;
    xs[c * 68 + tt] = (t >= 0) ? xb[(size_t)c * L_SZ + t] : 0.0f;
  }
  __syncthreads();
  int c = tid & 63;
  int tb = (tid >> 6) * 16;
  float wl[5];
#pragma unroll
  for (int k = 0; k < 5; k++) wl[k] = w[(c0 + c) * 5 + k];
  float bl = bias[c0 + c];
  size_t ob = ((size_t)b * L_SZ + t0 + tb) * DIM_SZ + c0 + c;
#pragma unroll
  for (int j = 0; j < 16; j++) {
    int t = tb + j;
    float acc = bl;
#pragma unroll
    for (int k = 0; k < 5; k++) acc += wl[k] * xs[c * 68 + t + 4 - k];
    float hf = bfhi_f(acc);
    h0h[ob + (size_t)j * DIM_SZ] = (ushort)(__float_as_uint(hf) >> 16);
    h0l[ob + (size_t)j * DIM_SZ] = f2bf(acc - hf);
  }
}

// ---- symmetric istft basis tables (window + sideband weights folded), fp32; + win ----
__global__ __launch_bounds__(256) void atab2_k(float* __restrict__ A,
                                               double* __restrict__ win) {
  int flat = blockIdx.x * 256 + threadIdx.x;  // over 2*576*544 = 626688
  int table = flat / ATSZ;
  int rem = flat - table * ATSZ;
  int n = rem / ATK, k = rem % ATK;
  const double W = 6.283185307179586476925287 / 1024.0;
  float val = 0.f;
  if (n <= 512 && k <= 512) {
    double wn = 0.5 * (1.0 - cos(W * (double)n));
    int mm = (k * n) & 1023;
    if (table == 0) {
      double wk = (k == 0 || k == 512) ? 1.0 : 2.0;
      val = (float)(wn * wk * cos(W * (double)mm));
    } else {
      val = (float)(wn * 2.0 * sin(W * (double)mm));
    }
  }
  A[flat] = val;
  if (flat < 1024) win[flat] = 0.5 * (1.0 - cos(W * (double)flat));
}

// ------- S prep: read fp32 (m,p) logits row, write Sre = mag*cos(p), Sim = mag*sin(p) --
__global__ __launch_bounds__(256) void sprep2_k(const float* __restrict__ mp,
                                                float* __restrict__ Sre,
                                                float* __restrict__ Sim) {
  size_t flat = (size_t)blockIdx.x * 256 + threadIdx.x;  // over 8*2048*544
  size_t row = flat / ATK;
  int k = (int)(flat % ATK);
  float re = 0.f, im = 0.f;
  if (k < 513) {
    const float* r = mp + row * SPADK;
    float m = r[k], p = r[513 + k];
    float mag = fminf(expf(m), 100.0f);
    re = mag * cosf(p);
    im = mag * sinf(p);
  }
  Sre[row * ATK + k] = re;
  Sim[row * ATK + k] = im;
}

// ---- fp32 GEMM, 64x64 tile, K-major LDS (used for the iSTFT basis GEMMs, M=576) ----
template <bool GELU>
__global__ __launch_bounds__(256) void gemm32t(const float* __restrict__ A, size_t a_bs,
                                               const float* __restrict__ Bm, size_t b_bs,
                                               const float* __restrict__ bias, int Mb,
                                               float* __restrict__ C, size_t c_bs, int ldc,
                                               int Mst, int K) {
  const int b = blockIdx.z;
  const int m0 = blockIdx.x * 64;
  const int t0 = blockIdx.y * 64;
  const int tid = threadIdx.x;
  __shared__ float As[32][68];   // [kk][m]
  __shared__ float Bs[32][68];   // [kk][t]
  const float* Ab = A + (size_t)b * a_bs + (size_t)m0 * K;
  const float* Bb = Bm + (size_t)b * b_bs + (size_t)t0 * K;
  const int tm = tid & 15;   // m-subtile
  const int tt = tid >> 4;   // t-subtile
  float acc[4][4] = {};
  for (int kt = 0; kt < K; kt += 32) {
#pragma unroll
    for (int i = 0; i < 2; i++) {
      int ch = i * 256 + tid;            // 0..511
      int row = ch >> 3, kc = (ch & 7) * 4;
      float4 a4 = *(const float4*)(Ab + (size_t)row * K + kt + kc);
      float4 b4 = *(const float4*)(Bb + (size_t)row * K + kt + kc);
      As[kc + 0][row] = a4.x; As[kc + 1][row] = a4.y;
      As[kc + 2][row] = a4.z; As[kc + 3][row] = a4.w;
      Bs[kc + 0][row] = b4.x; Bs[kc + 1][row] = b4.y;
      Bs[kc + 2][row] = b4.z; Bs[kc + 3][row] = b4.w;
    }
    __syncthreads();
#pragma unroll 8
    for (int kk = 0; kk < 32; kk++) {
      float4 am = *(const float4*)(&As[kk][tm * 4]);
      float4 bv = *(const float4*)(&Bs[kk][tt * 4]);
      const float* ap = &am.x;
      const float* bp = &bv.x;
#pragma unroll
      for (int i = 0; i < 4; i++)
#pragma unroll
        for (int j = 0; j < 4; j++) acc[i][j] += ap[i] * bp[j];
    }
    __syncthreads();
  }
  if (m0 + tm * 4 >= Mst) return;  // clip padded A rows
#pragma unroll
  for (int j = 0; j < 4; j++) {
    float4 v4;
    float* vp = &v4.x;
#pragma unroll
    for (int i = 0; i < 4; i++) {
      float v = acc[i][j];
      int m = m0 + tm * 4 + i;
      if (bias != nullptr && m < Mb) v += bias[m];
      if (GELU) v = 0.5f * v * (1.0f + erff(v * 0.70710678118654752f));
      vp[i] = v;
    }
    *(float4*)(C + (size_t)b * c_bs + (size_t)(t0 + tt * 4 + j) * ldc + m0 + tm * 4) = v4;
  }
}

// ---- bf16 3-term-split MFMA GEMM: C[b][t][m] = act(sum_k A[b][m][k]*B[b][t][k]+bias)
// A,B given as bf16 hi/lo pairs (value = hi + lo); D = Ah*Bh + Ah*Bl + Al*Bh in fp32 acc
// (omitted Al*Bl <= 2^-18|a||b|). 128x128 tile, 4 waves x (64x64), K-step 32.
// LDS rows padded to 40 ushorts (80 B): frag b128 reads are conflict-free in aggregate.
// Fragment layouts (mfma_f32_16x16x32_bf16): A: lane l = A[l&15][8*(l>>4)+j];
// B: lane l = B[8*(l>>4)+j][l&15] (= h[t=l&15][k]); D: col=l&15, row=(l>>4)*4+i (m89/m91).
template <bool GELU, bool OUTBF>
__global__ __launch_bounds__(256) void gemm_mfma(
    const ushort* __restrict__ Ah, const ushort* __restrict__ Al, size_t a_bs,
    const ushort* __restrict__ Bh, const ushort* __restrict__ Bl, size_t b_bs,
    const float* __restrict__ bias, int Mb,
    float* __restrict__ Cf, ushort* __restrict__ Chi, ushort* __restrict__ Clo,
    size_t c_bs, int ldc, int Mst, int K) {
  const int b = blockIdx.z;
  const int m0 = blockIdx.x * 128;
  const int t0 = blockIdx.y * 128;
  const int tid = threadIdx.x;
  const int l = tid & 63;
  const int w = tid >> 6;
  const int wm = (w & 1) * 64;
  const int wt = (w >> 1) * 64;
  const int tr = l & 15;   // frag row (m for A, t for B); also output col t
  const int ks = l >> 4;   // k-slot (8 bf16 each); also output row-quad selector
  __shared__ ushort Ash[128][40];
  __shared__ ushort Asl[128][40];
  __shared__ ushort Bsh[128][40];
  __shared__ ushort Bsl[128][40];
  const ushort* Abh = Ah + (size_t)b * a_bs + (size_t)m0 * K;
  const ushort* Abl = Al + (size_t)b * a_bs + (size_t)m0 * K;
  const ushort* Bbh = Bh + (size_t)b * b_bs + (size_t)t0 * K;
  const ushort* Bbl = Bl + (size_t)b * b_bs + (size_t)t0 * K;
  const int r0 = tid >> 2;         // staging row (chunk 1)
  const int r1 = r0 + 64;          // staging row (chunk 2)
  const int sl = (tid & 3) * 8;    // staging k-offset (8 ushorts = 16 B)
  f32x4 acc[4][4];
#pragma unroll
  for (int i = 0; i < 4; i++)
#pragma unroll
    for (int j = 0; j < 4; j++) acc[i][j] = (f32x4){0.f, 0.f, 0.f, 0.f};
  for (int kt = 0; kt < K; kt += 32) {
    uint4 va0 = *(const uint4*)(Abh + (size_t)r0 * K + kt + sl);
    uint4 va1 = *(const uint4*)(Abh + (size_t)r1 * K + kt + sl);
    uint4 vb0 = *(const uint4*)(Abl + (size_t)r0 * K + kt + sl);
    uint4 vb1 = *(const uint4*)(Abl + (size_t)r1 * K + kt + sl);
    uint4 vc0 = *(const uint4*)(Bbh + (size_t)r0 * K + kt + sl);
    uint4 vc1 = *(const uint4*)(Bbh + (size_t)r1 * K + kt + sl);
    uint4 vd0 = *(const uint4*)(Bbl + (size_t)r0 * K + kt + sl);
    uint4 vd1 = *(const uint4*)(Bbl + (size_t)r1 * K + kt + sl);
    *(uint4*)(&Ash[r0][sl]) = va0;
    *(uint4*)(&Ash[r1][sl]) = va1;
    *(uint4*)(&Asl[r0][sl]) = vb0;
    *(uint4*)(&Asl[r1][sl]) = vb1;
    *(uint4*)(&Bsh[r0][sl]) = vc0;
    *(uint4*)(&Bsh[r1][sl]) = vc1;
    *(uint4*)(&Bsl[r0][sl]) = vd0;
    *(uint4*)(&Bsl[r1][sl]) = vd1;
    __syncthreads();
    bfx8 ah[4], bh[4], tl[4];
#pragma unroll
    for (int f = 0; f < 4; f++) ah[f] = *(const bfx8*)(&Ash[wm + f * 16 + tr][ks * 8]);
#pragma unroll
    for (int f = 0; f < 4; f++) bh[f] = *(const bfx8*)(&Bsh[wt + f * 16 + tr][ks * 8]);
#pragma unroll
    for (int fi = 0; fi < 4; fi++)
#pragma unroll
      for (int fj = 0; fj < 4; fj++)
        acc[fi][fj] = __builtin_amdgcn_mfma_f32_16x16x32_bf16(ah[fi], bh[fj], acc[fi][fj], 0, 0, 0);
#pragma unroll
    for (int f = 0; f < 4; f++) tl[f] = *(const bfx8*)(&Bsl[wt + f * 16 + tr][ks * 8]);
#pragma unroll
    for (int fi = 0; fi < 4; fi++)
#pragma unroll
      for (int fj = 0; fj < 4; fj++)
        acc[fi][fj] = __builtin_amdgcn_mfma_f32_16x16x32_bf16(ah[fi], tl[fj], acc[fi][fj], 0, 0, 0);
#pragma unroll
    for (int f = 0; f < 4; f++) tl[f] = *(const bfx8*)(&Asl[wm + f * 16 + tr][ks * 8]);
#pragma unroll
    for (int fi = 0; fi < 4; fi++)
#pragma unroll
      for (int fj = 0; fj < 4; fj++)
        acc[fi][fj] = __builtin_amdgcn_mfma_f32_16x16x32_bf16(tl[fi], bh[fj], acc[fi][fj], 0, 0, 0);
    __syncthreads();
  }
  const int orow = ks * 4;
#pragma unroll
  for (int fi = 0; fi < 4; fi++) {
    int m = m0 + wm + fi * 16 + orow;   // quad base, multiple of 4
    if (m >= Mst) continue;             // clip padded A rows
#pragma unroll
    for (int fj = 0; fj < 4; fj++) {
      int t = t0 + wt + fj * 16 + tr;
      float o[4];
#pragma unroll
      for (int i = 0; i < 4; i++) {
        float xv = acc[fi][fj][i];
        if (bias != nullptr && (m + i) < Mb) xv += bias[m + i];
        if (GELU) xv = 0.5f * xv * (1.0f + erff(xv * 0.70710678118654752f));
        o[i] = xv;
      }
      if (OUTBF) {
        ushort hb[4], lb[4];
#pragma unroll
        for (int i = 0; i < 4; i++) {
          float hf = bfhi_f(o[i]);
          hb[i] = (ushort)(__float_as_uint(hf) >> 16);
          lb[i] = f2bf(o[i] - hf);
        }
        *(ushort4*)(Chi + (size_t)b * c_bs + (size_t)t * ldc + m) =
            make_ushort4(hb[0], hb[1], hb[2], hb[3]);
        *(ushort4*)(Clo + (size_t)b * c_bs + (size_t)t * ldc + m) =
            make_ushort4(lb[0], lb[1], lb[2], lb[3]);
      } else {
        *(float4*)(Cf + (size_t)b * c_bs + (size_t)t * ldc + m) =
            make_float4(o[0], o[1], o[2], o[3]);
      }
    }
  }
}

// ------- overlap-add + env normalize + crop, with symmetric frame reconstruction:
//   frame[tau][n] = C[tau][n] - D[tau][n]            (n <= 512)
//                 = C[tau][1024-n] + D[tau][1024-n]  (n >= 513)
__global__ __launch_bounds__(256) void ola_k(const float* __restrict__ CD,
                                             const double* __restrict__ win,
                                             float* __restrict__ out) {
  size_t flat = (size_t)blockIdx.x * 256 + threadIdx.x;  // over 8*524288
  int b = (int)(flat >> 19);
  int t = (int)(flat & 524287);
  int g = t + 384;  // PAD
  int r = g & 255, q4 = g >> 8;
  double acc = 0.0, env = 0.0;
#pragma unroll
  for (int q = 0; q < 4; q++) {
    int tau = q4 - q;
    int n = r + 256 * q;
    if (tau >= 0 && tau < 2048) {
      double w = win[n];
      int np = (n <= 512) ? n : 1024 - n;
      double sgn = (n <= 512) ? -1.0 : 1.0;
      const float* base = CD + ((size_t)b * 2048 + tau) * 1152 + np;
      acc += (double)base[0] + sgn * (double)base[576];
      env = fma(w, w, env);
    }
  }
  out[flat] = (float)(acc / (env * 1024.0));
}

extern "C" void kernel_launch(void* const* d_in, const int* in_sizes, int n_in, void* d_out,
                              int out_size, void* d_ws, size_t ws_size, hipStream_t stream) {
  (void)in_sizes; (void)n_in; (void)out_size; (void)ws_size;
  const float* x       = (const float*)d_in[0];
  const float* g_out   = (const float*)d_in[1];
  const float* dconv_w = (const float*)d_in[2];
  const float* dconv_b = (const float*)d_in[3];
  const float* p1_w    = (const float*)d_in[4];
  const float* p1_b    = (const float*)d_in[5];
  const float* p1_ain  = (const float*)d_in[6];
  const float* p1_aout = (const float*)d_in[7];
  const float* p2_w    = (const float*)d_in[8];
  const float* p2_b    = (const float*)d_in[9];
  const float* p2_ain  = (const float*)d_in[10];
  const float* p2_aout = (const float*)d_in[11];
  const float* out_w   = (const float*)d_in[12];
  const float* out_b   = (const float*)d_in[13];
  const float* out_ain = (const float*)d_in[14];
  const float* out_aout= (const float*)d_in[15];

  // Workspace: front tables + arena with time-shared slots; peak 176.8 MB < proven 192.3.
  char* ws = (char*)d_ws;
  float* ain1  = (float*)(ws + 0);
  float* aout1 = (float*)(ws + 196608);
  float* ain2  = (float*)(ws + 786432);
  float* aout2 = (float*)(ws + 1376256);
  float* ain3  = (float*)(ws + 1572864);
  float* aout3 = (float*)(ws + 1835008);
  float* Atab2 = (float*)(ws + 2360320);   // 2 tables * 576*544*4 = 2,506,752 B
  double* win  = (double*)(ws + 4867072);  // 8,192 B
  char*  arena = ws + 4875264;
  // arena lifetimes (stream-ordered, disjoint):
  //   [0, 100.66M):  h1_hi+h1_lo  -> mp (fp32, 71.3M) -> CD (75.5M)
  //   [100.66M, 134.2M): h0_hi+h0_lo -> h2_hi+h2_lo -> (dead) Sre spans from here
  //   [134.2M, 159.4M): w1 hi/lo -> w2 hi/lo -> w3 hi/lo -> (dead) Sre/Sim tail
  //   Sre [100.66M, 136.3M), Sim [136.3M, 172.0M)  (written after GEMM3)
  ushort* h1h = (ushort*)(arena + 0);
  ushort* h1l = (ushort*)(arena + 50331648);
  float*  mp  = (float*)(arena + 0);
  float*  CD  = (float*)(arena + 0);
  ushort* h0h = (ushort*)(arena + 100663296);
  ushort* h0l = (ushort*)(arena + 117440512);
  ushort* h2h = (ushort*)(arena + 100663296);
  ushort* h2l = (ushort*)(arena + 117440512);
  ushort* w1h = (ushort*)(arena + 134217728);
  ushort* w1l = (ushort*)(arena + 146800640);
  ushort* w2h = (ushort*)(arena + 134217728);
  ushort* w2l = (ushort*)(arena + 146800640);
  ushort* w3h = (ushort*)(arena + 134217728);
  ushort* w3l = (ushort*)(arena + 143654912);
  float*  Sre = (float*)(arena + 100663296);
  float*  Sim = (float*)(arena + 136314880);

  lora_vec_k<<<1536, 256, 0, stream>>>(p1_ain, 6144, g_out, ain1);
  lora_vec_k<<<4608, 256, 0, stream>>>(p1_aout, 18432, g_out, aout1);
  lora_vec_k<<<4608, 256, 0, stream>>>(p2_ain, 18432, g_out, ain2);
  lora_vec_k<<<1536, 256, 0, stream>>>(p2_aout, 6144, g_out, aout2);
  lora_vec_k<<<2048, 256, 0, stream>>>(out_ain, 8192, g_out, ain3);
  lora_vec_k<<<4104, 256, 0, stream>>>(out_aout, 16416, g_out, aout3);
  atab2_k<<<2448, 256, 0, stream>>>(Atab2, win);
  dconv_k<<<dim3(32, 8, 8), 256, 0, stream>>>(x, dconv_w, dconv_b, h0h, h0l);

  // layer 1: h1 = gelu(weff1 . h0 + b1)   (bf16-split MFMA)
  weff_k<<<dim3(3072, 1, 8), 256, 0, stream>>>(p1_w, ain1, aout1, w1h, w1l, 1536, 1536, 512, 12);
  gemm_mfma<true, true><<<dim3(12, 16, 8), 256, 0, stream>>>(
      w1h, w1l, (size_t)1536 * 512, h0h, h0l, (size_t)2048 * 512, p1_b, 1536,
      nullptr, h1h, h1l, (size_t)2048 * 1536, 1536, 1536, 512);

  // layer 2: h2 = gelu(weff2 . h1 + b2)
  weff_k<<<dim3(3072, 1, 8), 256, 0, stream>>>(p2_w, ain2, aout2, w2h, w2l, 512, 512, 1536, 12);
  gemm_mfma<true, true><<<dim3(4, 16, 8), 256, 0, stream>>>(
      w2h, w2l, (size_t)512 * 1536, h1h, h1l, (size_t)2048 * 1536, p2_b, 512,
      nullptr, h2h, h2l, (size_t)2048 * 512, 512, 512, 1536);

  // output projection: mp = weff3 . h2 + out_b  (fp32 out)
  weff_k<<<dim3(2304, 1, 8), 256, 0, stream>>>(out_w, ain3, aout3, w3h, w3l, 1026, 1152, 512, 16);
  gemm_mfma<false, false><<<dim3(9, 16, 8), 256, 0, stream>>>(
      w3h, w3l, (size_t)1152 * 512, h2h, h2l, (size_t)2048 * 512, out_b, 1026,
      mp, nullptr, nullptr, (size_t)2048 * SPADK, SPADK, SPADK, 512);

  sprep2_k<<<34816, 256, 0, stream>>>(mp, Sre, Sim);
  // cos-part -> CD[:, :, 0:576], sin-part -> CD[:, :, 576:1152]  (fp32 vector GEMMs)
  gemm32t<false><<<dim3(9, 32, 8), 256, 0, stream>>>(
      Atab2, (size_t)0, Sre, (size_t)2048 * ATK, nullptr, 0,
      CD, (size_t)2048 * 1152, 1152, 1152, ATK);
  gemm32t<false><<<dim3(9, 32, 8), 256, 0, stream>>>(
      Atab2 + ATSZ, (size_t)0, Sim, (size_t)2048 * ATK, nullptr, 0,
      CD + 576, (size_t)2048 * 1152, 1152, 1152, ATK);
  ola_k<<<16384, 256, 0, stream>>>(CD, win, (float*)d_out);
}

// Round 5
// 1048.341 us; speedup vs baseline: 2.6956x; 1.1553x over previous
//
#include <hip/hip_runtime.h>

#define L_SZ 2048
#define DIM_SZ 512
#define SPADK 1088   // mp logits row: 513 mag + 513 phase + 62 pad
#define ATK 544      // symmetric iSTFT GEMM K: 513 padded to 17*32
#define ATM 640      // symmetric iSTFT GEMM M: 513 padded to 5*128 (store-clipped at 576)
#define ATMV 576     // valid (write) M bound: 513 padded to multiple of 64
#define ATSZ (ATM * ATK)   // 348160 elems per table

typedef __attribute__((ext_vector_type(8))) short bfx8;
typedef __attribute__((ext_vector_type(4))) float f32x4;

// round-to-nearest-even fp32 -> bf16 helpers
__device__ __forceinline__ ushort f2bf(float v) {
  unsigned u = __float_as_uint(v);
  unsigned r = u + 0x7FFFu + ((u >> 16) & 1u);
  return (ushort)(r >> 16);
}
__device__ __forceinline__ float bfhi_f(float v) {
  unsigned u = __float_as_uint(v);
  unsigned r = (u + 0x7FFFu + ((u >> 16) & 1u)) & 0xFFFF0000u;
  return __uint_as_float(r);
}

// ---------------- per-batch LoRA factor GEMVs: out[b*rows + r] = dot(mat[r], g[b]) ----
__global__ __launch_bounds__(256) void lora_vec_k(const float* __restrict__ mat, int rows,
                                                  const float* __restrict__ g,
                                                  float* __restrict__ out) {
  __shared__ float gs[2048];
  int tid = threadIdx.x;
#pragma unroll
  for (int i = 0; i < 8; i++) gs[i * 256 + tid] = g[i * 256 + tid];
  __syncthreads();
  int row = blockIdx.x * 4 + (tid >> 6);
  if (row >= rows) return;
  int lane = tid & 63;
  float4 mv = *(const float4*)(mat + (size_t)row * 256 + lane * 4);
  float p[8];
#pragma unroll
  for (int b = 0; b < 8; b++) {
    const float* gb = gs + b * 256 + lane * 4;
    p[b] = mv.x * gb[0] + mv.y * gb[1] + mv.z * gb[2] + mv.w * gb[3];
  }
#pragma unroll
  for (int b = 0; b < 8; b++) {
    float v = p[b];
#pragma unroll
    for (int off = 32; off > 0; off >>= 1) v += __shfl_down(v, off, 64);
    if (lane == 0) out[(size_t)b * rows + row] = v;
  }
}

// --- W_eff[b][m][k] = W[m][k] + sum_r aout[b][r*M+m] * ain[b][k*R+r]; emit bf16 hi/lo --
__global__ __launch_bounds__(256) void weff_k(const float* __restrict__ W,
                                              const float* __restrict__ ain,
                                              const float* __restrict__ aout,
                                              ushort* __restrict__ oh,
                                              ushort* __restrict__ ol, int M, int Mpad,
                                              int K, int R) {
  int b = blockIdx.z;
  size_t flat = (size_t)blockIdx.x * 256 + threadIdx.x;  // over Mpad*K (exact multiple)
  int m = (int)(flat / K), k = (int)(flat % K);
  float v = 0.f;
  if (m < M) {
    v = W[(size_t)m * K + k];
    const float* ai = ain + ((size_t)b * K + k) * R;
    const float* ao = aout + (size_t)b * M * R + m;
    for (int r = 0; r < R; r++) v += ai[r] * ao[(size_t)r * M];
  }
  float hf = bfhi_f(v);
  size_t o = ((size_t)b * Mpad + m) * K + k;
  oh[o] = (ushort)(__float_as_uint(hf) >> 16);
  ol[o] = f2bf(v - hf);
}

// -- causal depthwise conv -> h0 as bf16 hi/lo: h0[b][t][c] = sum_k w[c][k]*x[b][c][t-k]
__global__ __launch_bounds__(256) void dconv_k(const float* __restrict__ x,
                                               const float* __restrict__ w,
                                               const float* __restrict__ bias,
                                               ushort* __restrict__ h0h,
                                               ushort* __restrict__ h0l) {
  const int t0 = blockIdx.x * 64;
  const int c0 = blockIdx.y * 64;
  const int b = blockIdx.z;
  const int tid = threadIdx.x;
  __shared__ float xs[64 * 68];
  const float* xb = x + ((size_t)b * DIM_SZ + c0) * L_SZ;
#pragma unroll
  for (int i = 0; i < 17; i++) {
    int flat = i * 256 + tid;  // 0..4351 = 64*68
    int c = flat / 68, tt = flat % 68;
    int t = t0 - 4 + tt;
    xs[c * 68 + tt] = (t >= 0) ? xb[(size_t)c * L_SZ + t] : 0.0f;
  }
  __syncthreads();
  int c = tid & 63;
  int tb = (tid >> 6) * 16;
  float wl[5];
#pragma unroll
  for (int k = 0; k < 5; k++) wl[k] = w[(c0 + c) * 5 + k];
  float bl = bias[c0 + c];
  size_t ob = ((size_t)b * L_SZ + t0 + tb) * DIM_SZ + c0 + c;
#pragma unroll
  for (int j = 0; j < 16; j++) {
    int t = tb + j;
    float acc = bl;
#pragma unroll
    for (int k = 0; k < 5; k++) acc += wl[k] * xs[c * 68 + t + 4 - k];
    float hf = bfhi_f(acc);
    h0h[ob + (size_t)j * DIM_SZ] = (ushort)(__float_as_uint(hf) >> 16);
    h0l[ob + (size_t)j * DIM_SZ] = f2bf(acc - hf);
  }
}

// ---- symmetric istft basis tables as bf16 hi/lo (window + sideband weights folded) ----
// table 0: Ac[n][k] = wn[n] * wk_k * cos(2*pi*k*n/1024)   (n,k in 0..512, rest 0)
// table 1: As[n][k] = wn[n] * 2    * sin(2*pi*k*n/1024)
__global__ __launch_bounds__(256) void atab2_k(ushort* __restrict__ Ah,
                                               ushort* __restrict__ Al,
                                               double* __restrict__ win) {
  int flat = blockIdx.x * 256 + threadIdx.x;  // over 2*640*544 = 696320
  int table = flat / ATSZ;
  int rem = flat - table * ATSZ;
  int n = rem / ATK, k = rem % ATK;
  const double W = 6.283185307179586476925287 / 1024.0;
  float val = 0.f;
  if (n <= 512 && k <= 512) {
    double wn = 0.5 * (1.0 - cos(W * (double)n));
    int mm = (k * n) & 1023;
    if (table == 0) {
      double wk = (k == 0 || k == 512) ? 1.0 : 2.0;
      val = (float)(wn * wk * cos(W * (double)mm));
    } else {
      val = (float)(wn * 2.0 * sin(W * (double)mm));
    }
  }
  float hf = bfhi_f(val);
  Ah[flat] = (ushort)(__float_as_uint(hf) >> 16);
  Al[flat] = f2bf(val - hf);
  if (flat < 1024) win[flat] = 0.5 * (1.0 - cos(W * (double)flat));
}

// ---- S prep: read fp32 (m,p) logits, emit S = mag*e^{ip} as bf16 hi/lo pairs ----
__global__ __launch_bounds__(256) void sprep2_k(const float* __restrict__ mp,
                                                ushort* __restrict__ Sreh,
                                                ushort* __restrict__ Srel,
                                                ushort* __restrict__ Simh,
                                                ushort* __restrict__ Siml) {
  size_t flat = (size_t)blockIdx.x * 256 + threadIdx.x;  // over 8*2048*544
  size_t row = flat / ATK;
  int k = (int)(flat % ATK);
  float re = 0.f, im = 0.f;
  if (k < 513) {
    const float* r = mp + row * SPADK;
    float m = r[k], p = r[513 + k];
    float mag = fminf(expf(m), 100.0f);
    re = mag * cosf(p);
    im = mag * sinf(p);
  }
  size_t o = row * ATK + k;
  float hr = bfhi_f(re), hi = bfhi_f(im);
  Sreh[o] = (ushort)(__float_as_uint(hr) >> 16);
  Srel[o] = f2bf(re - hr);
  Simh[o] = (ushort)(__float_as_uint(hi) >> 16);
  Siml[o] = f2bf(im - hi);
}

// ---- bf16 3-term-split MFMA GEMM: C[b][t][m] = act(sum_k A[b][m][k]*B[b][t][k]+bias)
// A,B given as bf16 hi/lo pairs (value = hi + lo); D = Ah*Bh + Ah*Bl + Al*Bh in fp32 acc
// (omitted Al*Bl <= 2^-18|a||b|). 128x128 tile, 4 waves x (64x64), K-step 32.
template <bool GELU, bool OUTBF>
__global__ __launch_bounds__(256) void gemm_mfma(
    const ushort* __restrict__ Ah, const ushort* __restrict__ Al, size_t a_bs,
    const ushort* __restrict__ Bh, const ushort* __restrict__ Bl, size_t b_bs,
    const float* __restrict__ bias, int Mb,
    float* __restrict__ Cf, ushort* __restrict__ Chi, ushort* __restrict__ Clo,
    size_t c_bs, int ldc, int Mst, int K) {
  const int b = blockIdx.z;
  const int m0 = blockIdx.x * 128;
  const int t0 = blockIdx.y * 128;
  const int tid = threadIdx.x;
  const int l = tid & 63;
  const int w = tid >> 6;
  const int wm = (w & 1) * 64;
  const int wt = (w >> 1) * 64;
  const int tr = l & 15;   // frag row (m for A, t for B); also output col t
  const int ks = l >> 4;   // k-slot (8 bf16 each); also output row-quad selector
  __shared__ ushort Ash[128][40];
  __shared__ ushort Asl[128][40];
  __shared__ ushort Bsh[128][40];
  __shared__ ushort Bsl[128][40];
  const ushort* Abh = Ah + (size_t)b * a_bs + (size_t)m0 * K;
  const ushort* Abl = Al + (size_t)b * a_bs + (size_t)m0 * K;
  const ushort* Bbh = Bh + (size_t)b * b_bs + (size_t)t0 * K;
  const ushort* Bbl = Bl + (size_t)b * b_bs + (size_t)t0 * K;
  const int r0 = tid >> 2;         // staging row (chunk 1)
  const int r1 = r0 + 64;          // staging row (chunk 2)
  const int sl = (tid & 3) * 8;    // staging k-offset (8 ushorts = 16 B)
  f32x4 acc[4][4];
#pragma unroll
  for (int i = 0; i < 4; i++)
#pragma unroll
    for (int j = 0; j < 4; j++) acc[i][j] = (f32x4){0.f, 0.f, 0.f, 0.f};
  for (int kt = 0; kt < K; kt += 32) {
    uint4 va0 = *(const uint4*)(Abh + (size_t)r0 * K + kt + sl);
    uint4 va1 = *(const uint4*)(Abh + (size_t)r1 * K + kt + sl);
    uint4 vb0 = *(const uint4*)(Abl + (size_t)r0 * K + kt + sl);
    uint4 vb1 = *(const uint4*)(Abl + (size_t)r1 * K + kt + sl);
    uint4 vc0 = *(const uint4*)(Bbh + (size_t)r0 * K + kt + sl);
    uint4 vc1 = *(const uint4*)(Bbh + (size_t)r1 * K + kt + sl);
    uint4 vd0 = *(const uint4*)(Bbl + (size_t)r0 * K + kt + sl);
    uint4 vd1 = *(const uint4*)(Bbl + (size_t)r1 * K + kt + sl);
    *(uint4*)(&Ash[r0][sl]) = va0;
    *(uint4*)(&Ash[r1][sl]) = va1;
    *(uint4*)(&Asl[r0][sl]) = vb0;
    *(uint4*)(&Asl[r1][sl]) = vb1;
    *(uint4*)(&Bsh[r0][sl]) = vc0;
    *(uint4*)(&Bsh[r1][sl]) = vc1;
    *(uint4*)(&Bsl[r0][sl]) = vd0;
    *(uint4*)(&Bsl[r1][sl]) = vd1;
    __syncthreads();
    bfx8 ah[4], bh[4], tl[4];
#pragma unroll
    for (int f = 0; f < 4; f++) ah[f] = *(const bfx8*)(&Ash[wm + f * 16 + tr][ks * 8]);
#pragma unroll
    for (int f = 0; f < 4; f++) bh[f] = *(const bfx8*)(&Bsh[wt + f * 16 + tr][ks * 8]);
#pragma unroll
    for (int fi = 0; fi < 4; fi++)
#pragma unroll
      for (int fj = 0; fj < 4; fj++)
        acc[fi][fj] = __builtin_amdgcn_mfma_f32_16x16x32_bf16(ah[fi], bh[fj], acc[fi][fj], 0, 0, 0);
#pragma unroll
    for (int f = 0; f < 4; f++) tl[f] = *(const bfx8*)(&Bsl[wt + f * 16 + tr][ks * 8]);
#pragma unroll
    for (int fi = 0; fi < 4; fi++)
#pragma unroll
      for (int fj = 0; fj < 4; fj++)
        acc[fi][fj] = __builtin_amdgcn_mfma_f32_16x16x32_bf16(ah[fi], tl[fj], acc[fi][fj], 0, 0, 0);
#pragma unroll
    for (int f = 0; f < 4; f++) tl[f] = *(const bfx8*)(&Asl[wm + f * 16 + tr][ks * 8]);
#pragma unroll
    for (int fi = 0; fi < 4; fi++)
#pragma unroll
      for (int fj = 0; fj < 4; fj++)
        acc[fi][fj] = __builtin_amdgcn_mfma_f32_16x16x32_bf16(tl[fi], bh[fj], acc[fi][fj], 0, 0, 0);
    __syncthreads();
  }
  const int orow = ks * 4;
#pragma unroll
  for (int fi = 0; fi < 4; fi++) {
    int m = m0 + wm + fi * 16 + orow;   // quad base, multiple of 4
    if (m >= Mst) continue;             // clip padded A rows
#pragma unroll
    for (int fj = 0; fj < 4; fj++) {
      int t = t0 + wt + fj * 16 + tr;
      float o[4];
#pragma unroll
      for (int i = 0; i < 4; i++) {
        float xv = acc[fi][fj][i];
        if (bias != nullptr && (m + i) < Mb) xv += bias[m + i];
        if (GELU) xv = 0.5f * xv * (1.0f + erff(xv * 0.70710678118654752f));
        o[i] = xv;
      }
      if (OUTBF) {
        ushort hb[4], lb[4];
#pragma unroll
        for (int i = 0; i < 4; i++) {
          float hf = bfhi_f(o[i]);
          hb[i] = (ushort)(__float_as_uint(hf) >> 16);
          lb[i] = f2bf(o[i] - hf);
        }
        *(ushort4*)(Chi + (size_t)b * c_bs + (size_t)t * ldc + m) =
            make_ushort4(hb[0], hb[1], hb[2], hb[3]);
        *(ushort4*)(Clo + (size_t)b * c_bs + (size_t)t * ldc + m) =
            make_ushort4(lb[0], lb[1], lb[2], lb[3]);
      } else {
        *(float4*)(Cf + (size_t)b * c_bs + (size_t)t * ldc + m) =
            make_float4(o[0], o[1], o[2], o[3]);
      }
    }
  }
}

// ------- overlap-add + env normalize + crop, with symmetric frame reconstruction:
//   frame[tau][n] = C[tau][n] - D[tau][n]            (n <= 512)
//                 = C[tau][1024-n] + D[tau][1024-n]  (n >= 513)
__global__ __launch_bounds__(256) void ola_k(const float* __restrict__ CD,
                                             const double* __restrict__ win,
                                             float* __restrict__ out) {
  size_t flat = (size_t)blockIdx.x * 256 + threadIdx.x;  // over 8*524288
  int b = (int)(flat >> 19);
  int t = (int)(flat & 524287);
  int g = t + 384;  // PAD
  int r = g & 255, q4 = g >> 8;
  double acc = 0.0, env = 0.0;
#pragma unroll
  for (int q = 0; q < 4; q++) {
    int tau = q4 - q;
    int n = r + 256 * q;
    if (tau >= 0 && tau < 2048) {
      double w = win[n];
      int np = (n <= 512) ? n : 1024 - n;
      double sgn = (n <= 512) ? -1.0 : 1.0;
      const float* base = CD + ((size_t)b * 2048 + tau) * 1152 + np;
      acc += (double)base[0] + sgn * (double)base[576];
      env = fma(w, w, env);
    }
  }
  out[flat] = (float)(acc / (env * 1024.0));
}

extern "C" void kernel_launch(void* const* d_in, const int* in_sizes, int n_in, void* d_out,
                              int out_size, void* d_ws, size_t ws_size, hipStream_t stream) {
  (void)in_sizes; (void)n_in; (void)out_size; (void)ws_size;
  const float* x       = (const float*)d_in[0];
  const float* g_out   = (const float*)d_in[1];
  const float* dconv_w = (const float*)d_in[2];
  const float* dconv_b = (const float*)d_in[3];
  const float* p1_w    = (const float*)d_in[4];
  const float* p1_b    = (const float*)d_in[5];
  const float* p1_ain  = (const float*)d_in[6];
  const float* p1_aout = (const float*)d_in[7];
  const float* p2_w    = (const float*)d_in[8];
  const float* p2_b    = (const float*)d_in[9];
  const float* p2_ain  = (const float*)d_in[10];
  const float* p2_aout = (const float*)d_in[11];
  const float* out_w   = (const float*)d_in[12];
  const float* out_b   = (const float*)d_in[13];
  const float* out_ain = (const float*)d_in[14];
  const float* out_aout= (const float*)d_in[15];

  // Workspace: front tables + arena with time-shared slots; peak ~177.1 MB < proven 192.3.
  char* ws = (char*)d_ws;
  float* ain1  = (float*)(ws + 0);
  float* aout1 = (float*)(ws + 196608);
  float* ain2  = (float*)(ws + 786432);
  float* aout2 = (float*)(ws + 1376256);
  float* ain3  = (float*)(ws + 1572864);
  float* aout3 = (float*)(ws + 1835008);
  ushort* tabh = (ushort*)(ws + 2360320);  // 2 tables * 640*544*2 = 1,392,640 B
  ushort* tabl = (ushort*)(ws + 3752960);  // 1,392,640 B
  double* win  = (double*)(ws + 5145600);  // 8,192 B
  char*  arena = ws + 5153792;
  // arena lifetimes (stream-ordered, disjoint):
  //   [0, 100.66M):  h1_hi+h1_lo  -> mp (fp32, 71.3M) -> CD (75.5M)
  //   [100.66M, 134.2M): h0_hi+h0_lo -> h2_hi+h2_lo -> (dead) S* spans from here
  //   [134.2M, 159.4M): w1 hi/lo -> w2 hi/lo -> w3 hi/lo -> (dead) S* tail
  //   S* (4 x 17.83M = 71.3M) at [100.66M, 172.0M), written after GEMM3
  ushort* h1h = (ushort*)(arena + 0);
  ushort* h1l = (ushort*)(arena + 50331648);
  float*  mp  = (float*)(arena + 0);
  float*  CD  = (float*)(arena + 0);
  ushort* h0h = (ushort*)(arena + 100663296);
  ushort* h0l = (ushort*)(arena + 117440512);
  ushort* h2h = (ushort*)(arena + 100663296);
  ushort* h2l = (ushort*)(arena + 117440512);
  ushort* w1h = (ushort*)(arena + 134217728);
  ushort* w1l = (ushort*)(arena + 146800640);
  ushort* w2h = (ushort*)(arena + 134217728);
  ushort* w2l = (ushort*)(arena + 146800640);
  ushort* w3h = (ushort*)(arena + 134217728);
  ushort* w3l = (ushort*)(arena + 143654912);
  ushort* Sreh = (ushort*)(arena + 100663296);
  ushort* Srel = (ushort*)(arena + 118489088);
  ushort* Simh = (ushort*)(arena + 136314880);
  ushort* Siml = (ushort*)(arena + 154140672);

  lora_vec_k<<<1536, 256, 0, stream>>>(p1_ain, 6144, g_out, ain1);
  lora_vec_k<<<4608, 256, 0, stream>>>(p1_aout, 18432, g_out, aout1);
  lora_vec_k<<<4608, 256, 0, stream>>>(p2_ain, 18432, g_out, ain2);
  lora_vec_k<<<1536, 256, 0, stream>>>(p2_aout, 6144, g_out, aout2);
  lora_vec_k<<<2048, 256, 0, stream>>>(out_ain, 8192, g_out, ain3);
  lora_vec_k<<<4104, 256, 0, stream>>>(out_aout, 16416, g_out, aout3);
  atab2_k<<<2720, 256, 0, stream>>>(tabh, tabl, win);
  dconv_k<<<dim3(32, 8, 8), 256, 0, stream>>>(x, dconv_w, dconv_b, h0h, h0l);

  // layer 1: h1 = gelu(weff1 . h0 + b1)   (bf16-split MFMA)
  weff_k<<<dim3(3072, 1, 8), 256, 0, stream>>>(p1_w, ain1, aout1, w1h, w1l, 1536, 1536, 512, 12);
  gemm_mfma<true, true><<<dim3(12, 16, 8), 256, 0, stream>>>(
      w1h, w1l, (size_t)1536 * 512, h0h, h0l, (size_t)2048 * 512, p1_b, 1536,
      nullptr, h1h, h1l, (size_t)2048 * 1536, 1536, 1536, 512);

  // layer 2: h2 = gelu(weff2 . h1 + b2)
  weff_k<<<dim3(3072, 1, 8), 256, 0, stream>>>(p2_w, ain2, aout2, w2h, w2l, 512, 512, 1536, 12);
  gemm_mfma<true, true><<<dim3(4, 16, 8), 256, 0, stream>>>(
      w2h, w2l, (size_t)512 * 1536, h1h, h1l, (size_t)2048 * 1536, p2_b, 512,
      nullptr, h2h, h2l, (size_t)2048 * 512, 512, 512, 1536);

  // output projection: mp = weff3 . h2 + out_b  (fp32 out)
  weff_k<<<dim3(2304, 1, 8), 256, 0, stream>>>(out_w, ain3, aout3, w3h, w3l, 1026, 1152, 512, 16);
  gemm_mfma<false, false><<<dim3(9, 16, 8), 256, 0, stream>>>(
      w3h, w3l, (size_t)1152 * 512, h2h, h2l, (size_t)2048 * 512, out_b, 1026,
      mp, nullptr, nullptr, (size_t)2048 * SPADK, SPADK, SPADK, 512);

  sprep2_k<<<34816, 256, 0, stream>>>(mp, Sreh, Srel, Simh, Siml);
  // cos-part -> CD[:, :, 0:576], sin-part -> CD[:, :, 576:1152]  (bf16-split MFMA;
  // store-clipped at ATMV=576 so zero pad rows don't clobber the other half)
  gemm_mfma<false, false><<<dim3(5, 16, 8), 256, 0, stream>>>(
      tabh, tabl, (size_t)0, Sreh, Srel, (size_t)2048 * ATK, nullptr, 0,
      CD, nullptr, nullptr, (size_t)2048 * 1152, 1152, ATMV, ATK);
  gemm_mfma<false, false><<<dim3(5, 16, 8), 256, 0, stream>>>(
      tabh + ATSZ, tabl + ATSZ, (size_t)0, Simh, Siml, (size_t)2048 * ATK, nullptr, 0,
      CD + 576, nullptr, nullptr, (size_t)2048 * 1152, 1152, ATMV, ATK);
  ola_k<<<16384, 256, 0, stream>>>(CD, win, (float*)d_out);
}

// Round 6
// 960.860 us; speedup vs baseline: 2.9410x; 1.0910x over previous
//
#include <hip/hip_runtime.h>

#define L_SZ 2048
#define DIM_SZ 512
#define SPADK 1088   // mp logits row: 513 mag + 513 phase + 62 pad (fp32)
#define ATK 544      // symmetric iSTFT GEMM K: 513 padded to 17*32
#define ATM 640      // symmetric iSTFT GEMM M: 513 padded to 5*128 (store-clipped at 576)
#define ATMV 576     // valid (write) M bound
#define ATSZ (ATM * ATK)       // logical elems per basis table
#define ATROW (2 * ATK)        // packed row pitch in ushorts (hi/lo interleaved)
#define ATSZ_PK (ATM * ATROW)  // packed ushorts per basis table

typedef __attribute__((ext_vector_type(8))) short bfx8;
typedef __attribute__((ext_vector_type(4))) float f32x4;

// round-to-nearest-even fp32 -> bf16 helpers
__device__ __forceinline__ ushort f2bf(float v) {
  unsigned u = __float_as_uint(v);
  unsigned r = u + 0x7FFFu + ((u >> 16) & 1u);
  return (ushort)(r >> 16);
}
__device__ __forceinline__ float bfhi_f(float v) {
  unsigned u = __float_as_uint(v);
  unsigned r = (u + 0x7FFFu + ((u >> 16) & 1u)) & 0xFFFF0000u;
  return __uint_as_float(r);
}

// async global->LDS 16B DMA (wave-uniform LDS base + lane*16)
__device__ __forceinline__ void gl_lds16(const void* g, void* l) {
  __builtin_amdgcn_global_load_lds(
      (const __attribute__((address_space(1))) unsigned int*)(uintptr_t)g,
      (__attribute__((address_space(3))) unsigned int*)(uintptr_t)l, 16, 0, 0);
}

// packed hi/lo write helper: row-pitch 2K ushorts; hi at chunk 2*(k>>3), lo at +8
__device__ __forceinline__ void pk_store(ushort* base, size_t row, int pitch2k, int k,
                                         float v) {
  size_t o = row * (size_t)pitch2k + (size_t)((k >> 3) * 16 + (k & 7));
  float hf = bfhi_f(v);
  base[o] = (ushort)(__float_as_uint(hf) >> 16);
  base[o + 8] = f2bf(v - hf);
}

// ---------------- per-batch LoRA factor GEMVs: out[b*rows + r] = dot(mat[r], g[b]) ----
__global__ __launch_bounds__(256) void lora_vec_k(const float* __restrict__ mat, int rows,
                                                  const float* __restrict__ g,
                                                  float* __restrict__ out) {
  __shared__ float gs[2048];
  int tid = threadIdx.x;
#pragma unroll
  for (int i = 0; i < 8; i++) gs[i * 256 + tid] = g[i * 256 + tid];
  __syncthreads();
  int row = blockIdx.x * 4 + (tid >> 6);
  if (row >= rows) return;
  int lane = tid & 63;
  float4 mv = *(const float4*)(mat + (size_t)row * 256 + lane * 4);
  float p[8];
#pragma unroll
  for (int b = 0; b < 8; b++) {
    const float* gb = gs + b * 256 + lane * 4;
    p[b] = mv.x * gb[0] + mv.y * gb[1] + mv.z * gb[2] + mv.w * gb[3];
  }
#pragma unroll
  for (int b = 0; b < 8; b++) {
    float v = p[b];
#pragma unroll
    for (int off = 32; off > 0; off >>= 1) v += __shfl_down(v, off, 64);
    if (lane == 0) out[(size_t)b * rows + row] = v;
  }
}

// --- W_eff[b][m][k] = W[m][k] + sum_r aout[..]*ain[..]; emit packed bf16 hi/lo ---
__global__ __launch_bounds__(256) void weff_k(const float* __restrict__ W,
                                              const float* __restrict__ ain,
                                              const float* __restrict__ aout,
                                              ushort* __restrict__ opk, int M, int Mpad,
                                              int K, int R) {
  int b = blockIdx.z;
  size_t flat = (size_t)blockIdx.x * 256 + threadIdx.x;  // over Mpad*K
  int m = (int)(flat / K), k = (int)(flat % K);
  float v = 0.f;
  if (m < M) {
    v = W[(size_t)m * K + k];
    const float* ai = ain + ((size_t)b * K + k) * R;
    const float* ao = aout + (size_t)b * M * R + m;
    for (int r = 0; r < R; r++) v += ai[r] * ao[(size_t)r * M];
  }
  pk_store(opk, (size_t)b * Mpad + m, 2 * K, k, v);
}

// -- causal depthwise conv -> packed h0: h0[b][t][c] = sum_k w[c][k]*x[b][c][t-k] --
__global__ __launch_bounds__(256) void dconv_k(const float* __restrict__ x,
                                               const float* __restrict__ w,
                                               const float* __restrict__ bias,
                                               ushort* __restrict__ h0pk) {
  const int t0 = blockIdx.x * 64;
  const int c0 = blockIdx.y * 64;
  const int b = blockIdx.z;
  const int tid = threadIdx.x;
  __shared__ float xs[64 * 68];
  const float* xb = x + ((size_t)b * DIM_SZ + c0) * L_SZ;
#pragma unroll
  for (int i = 0; i < 17; i++) {
    int flat = i * 256 + tid;  // 0..4351 = 64*68
    int c = flat / 68, tt = flat % 68;
    int t = t0 - 4 + tt;
    xs[c * 68 + tt] = (t >= 0) ? xb[(size_t)c * L_SZ + t] : 0.0f;
  }
  __syncthreads();
  int c = tid & 63;
  int tb = (tid >> 6) * 16;
  float wl[5];
#pragma unroll
  for (int k = 0; k < 5; k++) wl[k] = w[(c0 + c) * 5 + k];
  float bl = bias[c0 + c];
#pragma unroll
  for (int j = 0; j < 16; j++) {
    int t = tb + j;
    float acc = bl;
#pragma unroll
    for (int k = 0; k < 5; k++) acc += wl[k] * xs[c * 68 + t + 4 - k];
    pk_store(h0pk, (size_t)b * L_SZ + t0 + t, 2 * DIM_SZ, c0 + c, acc);
  }
}

// ---- symmetric istft basis tables (window+sideband folded), packed bf16 hi/lo ----
// table 0: Ac[n][k] = wn*wk*cos(2pi k n/1024); table 1: As[n][k] = wn*2*sin(2pi k n/1024)
__global__ __launch_bounds__(256) void atab2_k(ushort* __restrict__ tab,
                                               double* __restrict__ win) {
  int flat = blockIdx.x * 256 + threadIdx.x;  // over 2*640*544 = 696320
  int table = flat / ATSZ;
  int rem = flat - table * ATSZ;
  int n = rem / ATK, k = rem % ATK;
  const double W = 6.283185307179586476925287 / 1024.0;
  float val = 0.f;
  if (n <= 512 && k <= 512) {
    double wn = 0.5 * (1.0 - cos(W * (double)n));
    int mm = (k * n) & 1023;
    if (table == 0) {
      double wk = (k == 0 || k == 512) ? 1.0 : 2.0;
      val = (float)(wn * wk * cos(W * (double)mm));
    } else {
      val = (float)(wn * 2.0 * sin(W * (double)mm));
    }
  }
  pk_store(tab + (size_t)table * ATSZ_PK, (size_t)n, ATROW, k, val);
  if (flat < 1024) win[flat] = 0.5 * (1.0 - cos(W * (double)flat));
}

// ---- S prep: read fp32 (m,p) logits, emit packed Sre, Sim ----
__global__ __launch_bounds__(256) void sprep2_k(const float* __restrict__ mp,
                                                ushort* __restrict__ Sre,
                                                ushort* __restrict__ Sim) {
  size_t flat = (size_t)blockIdx.x * 256 + threadIdx.x;  // over 8*2048*544
  size_t row = flat / ATK;
  int k = (int)(flat % ATK);
  float re = 0.f, im = 0.f;
  if (k < 513) {
    const float* r = mp + row * SPADK;
    float m = r[k], p = r[513 + k];
    float mag = fminf(expf(m), 100.0f);
    re = mag * cosf(p);
    im = mag * sinf(p);
  }
  pk_store(Sre, row, ATROW, k, re);
  pk_store(Sim, row, ATROW, k, im);
}

// ---- bf16 3-term-split MFMA GEMM, m97 structure:
//  C[b][t][m] = act(sum_k A[b][m][k]*B[b][t][k] + bias[m]);  A,B packed hi/lo.
//  128x128 tile, 4 waves x (64x64), K-step 32; global_load_lds(16B) staging into
//  linear LDS [128][64us] with both-sides XOR swizzle: LDS chunk c holds global
//  chunk c ^ (row&7) (pre-swizzled source), reads use the same XOR -> 2-way banks.
template <bool GELU, bool OUTBF>
__global__ __launch_bounds__(256) void gemm_pk(
    const ushort* __restrict__ Apk, size_t a_bs,
    const ushort* __restrict__ Bpk, size_t b_bs,
    const float* __restrict__ bias, int Mb,
    float* __restrict__ Cf, ushort* __restrict__ Cpk, size_t c_bs, int ldc,
    int Mst, int K) {
  const int b = blockIdx.z;
  const int m0 = blockIdx.x * 128;
  const int t0 = blockIdx.y * 128;
  const int tid = threadIdx.x;
  const int l = tid & 63;
  const int w = tid >> 6;
  const int wm = (w & 1) * 64;
  const int wt = (w >> 1) * 64;
  const int tr = l & 15;   // frag row within 16 (m for A, t for B); also output col t
  const int ks = l >> 4;   // k-slot (8 bf16); also output row-quad selector
  __shared__ ushort As[128 * 64];
  __shared__ ushort Bs[128 * 64];
  const int pitch = 2 * K;
  // staging lane constants: wave w stages A rows [w*32,w*32+32) and B rows likewise,
  // 4 gl_lds16 each (8 rows x 128B per call). Pre-swizzled source chunk = sc ^ sr.
  const int sr = l >> 3;         // lds row within 8-row group = (lds_row & 7)
  const int sc = l & 7;          // lds 16B-chunk within row
  const int scs = sc ^ sr;       // global chunk fetched into (row, sc)
  const ushort* gA = Apk + (size_t)b * a_bs + (size_t)(m0 + w * 32 + sr) * pitch + scs * 8;
  const ushort* gB = Bpk + (size_t)b * b_bs + (size_t)(t0 + w * 32 + sr) * pitch + scs * 8;
  ushort* lA = As + w * 32 * 64;
  ushort* lB = Bs + w * 32 * 64;
  // fragment read offsets (ushorts); logical chunk 2ks=hi, 2ks+1=lo; row&7 = tr&7
  const int swz = tr & 7;
  const int a_hi = (wm + tr) * 64 + (((2 * ks) ^ swz) * 8);
  const int a_lo = (wm + tr) * 64 + (((2 * ks + 1) ^ swz) * 8);
  const int b_hi = (wt + tr) * 64 + (((2 * ks) ^ swz) * 8);
  const int b_lo = (wt + tr) * 64 + (((2 * ks + 1) ^ swz) * 8);
  f32x4 acc[4][4];
#pragma unroll
  for (int i = 0; i < 4; i++)
#pragma unroll
    for (int j = 0; j < 4; j++) acc[i][j] = (f32x4){0.f, 0.f, 0.f, 0.f};
  for (int kt = 0; kt < K; kt += 32) {
    if (kt) __syncthreads();  // previous tile's reads complete before overwrite
    const ushort* ga = gA + kt * 2;
    const ushort* gb = gB + kt * 2;
#pragma unroll
    for (int i = 0; i < 4; i++) {
      gl_lds16(ga + (size_t)(i * 8) * pitch, lA + i * 8 * 64);
      gl_lds16(gb + (size_t)(i * 8) * pitch, lB + i * 8 * 64);
    }
    __syncthreads();  // compiler drains vmcnt(0) before s_barrier -> tile ready
    bfx8 ah[4], bh[4], tl[4];
#pragma unroll
    for (int f = 0; f < 4; f++) ah[f] = *(const bfx8*)(As + a_hi + f * 1024);
#pragma unroll
    for (int f = 0; f < 4; f++) bh[f] = *(const bfx8*)(Bs + b_hi + f * 1024);
#pragma unroll
    for (int fi = 0; fi < 4; fi++)
#pragma unroll
      for (int fj = 0; fj < 4; fj++)
        acc[fi][fj] = __builtin_amdgcn_mfma_f32_16x16x32_bf16(ah[fi], bh[fj], acc[fi][fj], 0, 0, 0);
#pragma unroll
    for (int f = 0; f < 4; f++) tl[f] = *(const bfx8*)(Bs + b_lo + f * 1024);
#pragma unroll
    for (int fi = 0; fi < 4; fi++)
#pragma unroll
      for (int fj = 0; fj < 4; fj++)
        acc[fi][fj] = __builtin_amdgcn_mfma_f32_16x16x32_bf16(ah[fi], tl[fj], acc[fi][fj], 0, 0, 0);
#pragma unroll
    for (int f = 0; f < 4; f++) tl[f] = *(const bfx8*)(As + a_lo + f * 1024);
#pragma unroll
    for (int fi = 0; fi < 4; fi++)
#pragma unroll
      for (int fj = 0; fj < 4; fj++)
        acc[fi][fj] = __builtin_amdgcn_mfma_f32_16x16x32_bf16(tl[fi], bh[fj], acc[fi][fj], 0, 0, 0);
  }
  const int orow = ks * 4;
#pragma unroll
  for (int fi = 0; fi < 4; fi++) {
    int m = m0 + wm + fi * 16 + orow;   // quad base, multiple of 4
    if (m >= Mst) continue;             // clip padded A rows
#pragma unroll
    for (int fj = 0; fj < 4; fj++) {
      int t = t0 + wt + fj * 16 + tr;
      float o[4];
#pragma unroll
      for (int i = 0; i < 4; i++) {
        float xv = acc[fi][fj][i];
        if (bias != nullptr && (m + i) < Mb) xv += bias[m + i];
        if (GELU) xv = 0.5f * xv * (1.0f + erff(xv * 0.70710678118654752f));
        o[i] = xv;
      }
      if (OUTBF) {
        // packed output: row t, k-dim = m; pitch = 2*ldc; m&7 in {0,4}
        size_t base = (size_t)b * c_bs + (size_t)t * (2 * ldc) + ((m >> 3) * 16 + (m & 7));
        ushort hb[4], lb[4];
#pragma unroll
        for (int i = 0; i < 4; i++) {
          float hf = bfhi_f(o[i]);
          hb[i] = (ushort)(__float_as_uint(hf) >> 16);
          lb[i] = f2bf(o[i] - hf);
        }
        *(ushort4*)(Cpk + base) = make_ushort4(hb[0], hb[1], hb[2], hb[3]);
        *(ushort4*)(Cpk + base + 8) = make_ushort4(lb[0], lb[1], lb[2], lb[3]);
      } else {
        *(float4*)(Cf + (size_t)b * c_bs + (size_t)t * ldc + m) =
            make_float4(o[0], o[1], o[2], o[3]);
      }
    }
  }
}

// ------- overlap-add + env normalize + crop, with symmetric frame reconstruction:
//   frame[tau][n] = C[tau][n] - D[tau][n]            (n <= 512)
//                 = C[tau][1024-n] + D[tau][1024-n]  (n >= 513)
__global__ __launch_bounds__(256) void ola_k(const float* __restrict__ CD,
                                             const double* __restrict__ win,
                                             float* __restrict__ out) {
  size_t flat = (size_t)blockIdx.x * 256 + threadIdx.x;  // over 8*524288
  int b = (int)(flat >> 19);
  int t = (int)(flat & 524287);
  int g = t + 384;  // PAD
  int r = g & 255, q4 = g >> 8;
  double acc = 0.0, env = 0.0;
#pragma unroll
  for (int q = 0; q < 4; q++) {
    int tau = q4 - q;
    int n = r + 256 * q;
    if (tau >= 0 && tau < 2048) {
      double w = win[n];
      int np = (n <= 512) ? n : 1024 - n;
      double sgn = (n <= 512) ? -1.0 : 1.0;
      const float* base = CD + ((size_t)b * 2048 + tau) * 1152 + np;
      acc += (double)base[0] + sgn * (double)base[576];
      env = fma(w, w, env);
    }
  }
  out[flat] = (float)(acc / (env * 1024.0));
}

extern "C" void kernel_launch(void* const* d_in, const int* in_sizes, int n_in, void* d_out,
                              int out_size, void* d_ws, size_t ws_size, hipStream_t stream) {
  (void)in_sizes; (void)n_in; (void)out_size; (void)ws_size;
  const float* x       = (const float*)d_in[0];
  const float* g_out   = (const float*)d_in[1];
  const float* dconv_w = (const float*)d_in[2];
  const float* dconv_b = (const float*)d_in[3];
  const float* p1_w    = (const float*)d_in[4];
  const float* p1_b    = (const float*)d_in[5];
  const float* p1_ain  = (const float*)d_in[6];
  const float* p1_aout = (const float*)d_in[7];
  const float* p2_w    = (const float*)d_in[8];
  const float* p2_b    = (const float*)d_in[9];
  const float* p2_ain  = (const float*)d_in[10];
  const float* p2_aout = (const float*)d_in[11];
  const float* out_w   = (const float*)d_in[12];
  const float* out_b   = (const float*)d_in[13];
  const float* out_ain = (const float*)d_in[14];
  const float* out_aout= (const float*)d_in[15];

  // Workspace: front tables + arena with time-shared slots; peak ~177.1 MB < proven 192.3.
  char* ws = (char*)d_ws;
  float* ain1  = (float*)(ws + 0);
  float* aout1 = (float*)(ws + 196608);
  float* ain2  = (float*)(ws + 786432);
  float* aout2 = (float*)(ws + 1376256);
  float* ain3  = (float*)(ws + 1572864);
  float* aout3 = (float*)(ws + 1835008);
  ushort* tab  = (ushort*)(ws + 2360320);  // 2 tables * 640*1088*2 B = 2,785,280 B
  double* win  = (double*)(ws + 5145600);  // 8,192 B
  char*  arena = ws + 5153792;
  // arena lifetimes (stream-ordered, disjoint):
  //   [0, 100.66M):  h1 (packed) -> mp (fp32, 71.3M) -> CD (75.5M)
  //   [100.66M, 134.2M): h0 -> h2 (packed)
  //   [134.2M, 159.4M): w1 -> w2 -> w3 (packed)
  //   Sre [100.66M, 136.31M), Sim [136.31M, 171.97M)  (after GEMM3; h2/w3 dead)
  ushort* h1  = (ushort*)(arena + 0);
  float*  mp  = (float*)(arena + 0);
  float*  CD  = (float*)(arena + 0);
  ushort* h0  = (ushort*)(arena + 100663296);
  ushort* h2  = (ushort*)(arena + 100663296);
  ushort* w1  = (ushort*)(arena + 134217728);
  ushort* w2  = (ushort*)(arena + 134217728);
  ushort* w3  = (ushort*)(arena + 134217728);
  ushort* Sre = (ushort*)(arena + 100663296);
  ushort* Sim = (ushort*)(arena + 136314880);

  lora_vec_k<<<1536, 256, 0, stream>>>(p1_ain, 6144, g_out, ain1);
  lora_vec_k<<<4608, 256, 0, stream>>>(p1_aout, 18432, g_out, aout1);
  lora_vec_k<<<4608, 256, 0, stream>>>(p2_ain, 18432, g_out, ain2);
  lora_vec_k<<<1536, 256, 0, stream>>>(p2_aout, 6144, g_out, aout2);
  lora_vec_k<<<2048, 256, 0, stream>>>(out_ain, 8192, g_out, ain3);
  lora_vec_k<<<4104, 256, 0, stream>>>(out_aout, 16416, g_out, aout3);
  atab2_k<<<2720, 256, 0, stream>>>(tab, win);
  dconv_k<<<dim3(32, 8, 8), 256, 0, stream>>>(x, dconv_w, dconv_b, h0);

  // layer 1: h1 = gelu(weff1 . h0 + b1)
  weff_k<<<dim3(3072, 1, 8), 256, 0, stream>>>(p1_w, ain1, aout1, w1, 1536, 1536, 512, 12);
  gemm_pk<true, true><<<dim3(12, 16, 8), 256, 0, stream>>>(
      w1, (size_t)1536 * 1024, h0, (size_t)2048 * 1024, p1_b, 1536,
      nullptr, h1, (size_t)2048 * 3072, 1536, 1536, 512);

  // layer 2: h2 = gelu(weff2 . h1 + b2)
  weff_k<<<dim3(3072, 1, 8), 256, 0, stream>>>(p2_w, ain2, aout2, w2, 512, 512, 1536, 12);
  gemm_pk<true, true><<<dim3(4, 16, 8), 256, 0, stream>>>(
      w2, (size_t)512 * 3072, h1, (size_t)2048 * 3072, p2_b, 512,
      nullptr, h2, (size_t)2048 * 1024, 512, 512, 1536);

  // output projection: mp = weff3 . h2 + out_b  (fp32 out)
  weff_k<<<dim3(2304, 1, 8), 256, 0, stream>>>(out_w, ain3, aout3, w3, 1026, 1152, 512, 16);
  gemm_pk<false, false><<<dim3(9, 16, 8), 256, 0, stream>>>(
      w3, (size_t)1152 * 1024, h2, (size_t)2048 * 1024, out_b, 1026,
      mp, nullptr, (size_t)2048 * SPADK, SPADK, SPADK, 512);

  sprep2_k<<<34816, 256, 0, stream>>>(mp, Sre, Sim);
  // cos-part -> CD[:, :, 0:576], sin-part -> CD[:, :, 576:1152]
  gemm_pk<false, false><<<dim3(5, 16, 8), 256, 0, stream>>>(
      tab, (size_t)0, Sre, (size_t)2048 * ATROW, nullptr, 0,
      CD, nullptr, (size_t)2048 * 1152, 1152, ATMV, ATK);
  gemm_pk<false, false><<<dim3(5, 16, 8), 256, 0, stream>>>(
      tab + ATSZ_PK, (size_t)0, Sim, (size_t)2048 * ATROW, nullptr, 0,
      CD + 576, nullptr, (size_t)2048 * 1152, 1152, ATMV, ATK);
  ola_k<<<16384, 256, 0, stream>>>(CD, win, (float*)d_out);
}

// Round 7
// 733.013 us; speedup vs baseline: 3.8552x; 1.3108x over previous
//
#include <hip/hip_runtime.h>

#define L_SZ 2048
#define DIM_SZ 512
#define SPADK 1088   // mp logits row: 513 mag + 513 phase + 62 pad (fp32)
#define ATK 544      // symmetric iSTFT GEMM K: 513 padded to 17*32
#define ATM 640      // symmetric iSTFT GEMM M: 513 padded to 5*128 (store-clipped at 576)
#define ATMV 576     // valid (write) M bound
#define ATSZ (ATM * ATK)       // logical elems per basis table
#define ATROW (2 * ATK)        // packed row pitch in ushorts (hi/lo interleaved)
#define ATSZ_PK (ATM * ATROW)  // packed ushorts per basis table

typedef __attribute__((ext_vector_type(8))) short bfx8;
typedef __attribute__((ext_vector_type(4))) float f32x4;

// round-to-nearest-even fp32 -> bf16 helpers
__device__ __forceinline__ ushort f2bf(float v) {
  unsigned u = __float_as_uint(v);
  unsigned r = u + 0x7FFFu + ((u >> 16) & 1u);
  return (ushort)(r >> 16);
}
__device__ __forceinline__ float bfhi_f(float v) {
  unsigned u = __float_as_uint(v);
  unsigned r = (u + 0x7FFFu + ((u >> 16) & 1u)) & 0xFFFF0000u;
  return __uint_as_float(r);
}

// async global->LDS 16B DMA (wave-uniform LDS base + lane*16)
__device__ __forceinline__ void gl_lds16(const void* g, void* l) {
  __builtin_amdgcn_global_load_lds(
      (const __attribute__((address_space(1))) unsigned int*)(uintptr_t)g,
      (__attribute__((address_space(3))) unsigned int*)(uintptr_t)l, 16, 0, 0);
}

// packed hi/lo write helper (scalar producers): row-pitch 2K ushorts
__device__ __forceinline__ void pk_store(ushort* base, size_t row, int pitch2k, int k,
                                         float v) {
  size_t o = row * (size_t)pitch2k + (size_t)((k >> 3) * 16 + (k & 7));
  float hf = bfhi_f(v);
  base[o] = (ushort)(__float_as_uint(hf) >> 16);
  base[o + 8] = f2bf(v - hf);
}

// ---------------- per-batch LoRA factor GEMVs: out[b*rows + r] = dot(mat[r], g[b]) ----
// tR > 0: rows = K*R with r fastest; write TRANSPOSED out[b][r][k] (k = row/tR).
__global__ __launch_bounds__(256) void lora_vec_k(const float* __restrict__ mat, int rows,
                                                  const float* __restrict__ g,
                                                  float* __restrict__ out,
                                                  int tK, int tR) {
  __shared__ float gs[2048];
  int tid = threadIdx.x;
#pragma unroll
  for (int i = 0; i < 8; i++) gs[i * 256 + tid] = g[i * 256 + tid];
  __syncthreads();
  int row = blockIdx.x * 4 + (tid >> 6);
  if (row >= rows) return;
  int lane = tid & 63;
  float4 mv = *(const float4*)(mat + (size_t)row * 256 + lane * 4);
  float p[8];
#pragma unroll
  for (int b = 0; b < 8; b++) {
    const float* gb = gs + b * 256 + lane * 4;
    p[b] = mv.x * gb[0] + mv.y * gb[1] + mv.z * gb[2] + mv.w * gb[3];
  }
#pragma unroll
  for (int b = 0; b < 8; b++) {
    float v = p[b];
#pragma unroll
    for (int off = 32; off > 0; off >>= 1) v += __shfl_down(v, off, 64);
    if (lane == 0) {
      size_t o;
      if (tR > 0) {
        int kk = row / tR, rr = row - kk * tR;
        o = ((size_t)b * tR + rr) * tK + kk;
      } else {
        o = (size_t)b * rows + row;
      }
      out[o] = v;
    }
  }
}

// --- W_eff[b][m][k] = W[m][k] + sum_r aout[b][r][m] * ain_t[b][r][k]; packed bf16 out.
// 8 k's per thread: acc[8] chains, coalesced ain_t loads, broadcast aout, uint4 stores.
__global__ __launch_bounds__(256) void weff_k(const float* __restrict__ W,
                                              const float* __restrict__ aint,
                                              const float* __restrict__ aout,
                                              ushort* __restrict__ opk, int M, int Mpad,
                                              int K, int R) {
  const int b = blockIdx.z;
  const int kc8 = K >> 3;
  int flat = blockIdx.x * 256 + threadIdx.x;  // over Mpad * K/8 (exact multiple)
  int m = flat / kc8, kc = flat - m * kc8;
  float acc[8] = {};
  if (m < M) {
    const float4* wv = (const float4*)(W + (size_t)m * K + kc * 8);
    float4 w0 = wv[0], w1 = wv[1];
    acc[0] = w0.x; acc[1] = w0.y; acc[2] = w0.z; acc[3] = w0.w;
    acc[4] = w1.x; acc[5] = w1.y; acc[6] = w1.z; acc[7] = w1.w;
    const float* ai = aint + (size_t)b * R * K + kc * 8;
    const float* ao = aout + (size_t)b * M * R + m;
    for (int r = 0; r < R; r++) {
      float aor = ao[(size_t)r * M];
      const float4* av = (const float4*)(ai + (size_t)r * K);
      float4 a0 = av[0], a1 = av[1];
      acc[0] += aor * a0.x; acc[1] += aor * a0.y;
      acc[2] += aor * a0.z; acc[3] += aor * a0.w;
      acc[4] += aor * a1.x; acc[5] += aor * a1.y;
      acc[6] += aor * a1.z; acc[7] += aor * a1.w;
    }
  }
  unsigned hw[4], lw[4];
#pragma unroll
  for (int i = 0; i < 4; i++) {
    float h0 = bfhi_f(acc[2 * i]), h1 = bfhi_f(acc[2 * i + 1]);
    unsigned u0 = __float_as_uint(h0) >> 16, u1 = __float_as_uint(h1) >> 16;
    hw[i] = u0 | (u1 << 16);
    unsigned l0 = f2bf(acc[2 * i] - h0), l1 = f2bf(acc[2 * i + 1] - h1);
    lw[i] = l0 | (l1 << 16);
  }
  ushort* o = opk + ((size_t)b * Mpad + m) * (size_t)(2 * K) + kc * 16;
  *(uint4*)(o) = make_uint4(hw[0], hw[1], hw[2], hw[3]);
  *(uint4*)(o + 8) = make_uint4(lw[0], lw[1], lw[2], lw[3]);
}

// -- causal depthwise conv -> packed h0: h0[b][t][c] = sum_k w[c][k]*x[b][c][t-k] --
__global__ __launch_bounds__(256) void dconv_k(const float* __restrict__ x,
                                               const float* __restrict__ w,
                                               const float* __restrict__ bias,
                                               ushort* __restrict__ h0pk) {
  const int t0 = blockIdx.x * 64;
  const int c0 = blockIdx.y * 64;
  const int b = blockIdx.z;
  const int tid = threadIdx.x;
  __shared__ float xs[64 * 68];
  const float* xb = x + ((size_t)b * DIM_SZ + c0) * L_SZ;
#pragma unroll
  for (int i = 0; i < 17; i++) {
    int flat = i * 256 + tid;  // 0..4351 = 64*68
    int c = flat / 68, tt = flat % 68;
    int t = t0 - 4 + tt;
    xs[c * 68 + tt] = (t >= 0) ? xb[(size_t)c * L_SZ + t] : 0.0f;
  }
  __syncthreads();
  int c = tid & 63;
  int tb = (tid >> 6) * 16;
  float wl[5];
#pragma unroll
  for (int k = 0; k < 5; k++) wl[k] = w[(c0 + c) * 5 + k];
  float bl = bias[c0 + c];
#pragma unroll
  for (int j = 0; j < 16; j++) {
    int t = tb + j;
    float acc = bl;
#pragma unroll
    for (int k = 0; k < 5; k++) acc += wl[k] * xs[c * 68 + t + 4 - k];
    pk_store(h0pk, (size_t)b * L_SZ + t0 + t, 2 * DIM_SZ, c0 + c, acc);
  }
}

// ---- symmetric istft basis tables (window+sideband folded), packed bf16 hi/lo ----
__global__ __launch_bounds__(256) void atab2_k(ushort* __restrict__ tab,
                                               double* __restrict__ win) {
  int flat = blockIdx.x * 256 + threadIdx.x;  // over 2*640*544 = 696320
  int table = flat / ATSZ;
  int rem = flat - table * ATSZ;
  int n = rem / ATK, k = rem % ATK;
  const double W = 6.283185307179586476925287 / 1024.0;
  float val = 0.f;
  if (n <= 512 && k <= 512) {
    double wn = 0.5 * (1.0 - cos(W * (double)n));
    int mm = (k * n) & 1023;
    if (table == 0) {
      double wk = (k == 0 || k == 512) ? 1.0 : 2.0;
      val = (float)(wn * wk * cos(W * (double)mm));
    } else {
      val = (float)(wn * 2.0 * sin(W * (double)mm));
    }
  }
  pk_store(tab + (size_t)table * ATSZ_PK, (size_t)n, ATROW, k, val);
  if (flat < 1024) win[flat] = 0.5 * (1.0 - cos(W * (double)flat));
}

// ---- S prep: read fp32 (m,p) logits, emit packed Sre, Sim ----
__global__ __launch_bounds__(256) void sprep2_k(const float* __restrict__ mp,
                                                ushort* __restrict__ Sre,
                                                ushort* __restrict__ Sim) {
  size_t flat = (size_t)blockIdx.x * 256 + threadIdx.x;  // over 8*2048*544
  size_t row = flat / ATK;
  int k = (int)(flat % ATK);
  float re = 0.f, im = 0.f;
  if (k < 513) {
    const float* r = mp + row * SPADK;
    float m = r[k], p = r[513 + k];
    float mag = fminf(expf(m), 100.0f);
    re = mag * cosf(p);
    im = mag * sinf(p);
  }
  pk_store(Sre, row, ATROW, k, re);
  pk_store(Sim, row, ATROW, k, im);
}

// ---- bf16 3-term-split MFMA GEMM, m97 structure (see R6 notes) ----
template <bool GELU, bool OUTBF>
__global__ __launch_bounds__(256) void gemm_pk(
    const ushort* __restrict__ Apk, size_t a_bs,
    const ushort* __restrict__ Bpk, size_t b_bs,
    const float* __restrict__ bias, int Mb,
    float* __restrict__ Cf, ushort* __restrict__ Cpk, size_t c_bs, int ldc,
    int Mst, int K) {
  const int b = blockIdx.z;
  const int m0 = blockIdx.x * 128;
  const int t0 = blockIdx.y * 128;
  const int tid = threadIdx.x;
  const int l = tid & 63;
  const int w = tid >> 6;
  const int wm = (w & 1) * 64;
  const int wt = (w >> 1) * 64;
  const int tr = l & 15;   // frag row within 16; also output col t
  const int ks = l >> 4;   // k-slot (8 bf16); also output row-quad selector
  __shared__ ushort As[128 * 64];
  __shared__ ushort Bs[128 * 64];
  const int pitch = 2 * K;
  const int sr = l >> 3;         // lds row within 8-row group
  const int sc = l & 7;          // lds 16B-chunk within row
  const int scs = sc ^ sr;       // pre-swizzled global chunk
  const ushort* gA = Apk + (size_t)b * a_bs + (size_t)(m0 + w * 32 + sr) * pitch + scs * 8;
  const ushort* gB = Bpk + (size_t)b * b_bs + (size_t)(t0 + w * 32 + sr) * pitch + scs * 8;
  ushort* lA = As + w * 32 * 64;
  ushort* lB = Bs + w * 32 * 64;
  const int swz = tr & 7;
  const int a_hi = (wm + tr) * 64 + (((2 * ks) ^ swz) * 8);
  const int a_lo = (wm + tr) * 64 + (((2 * ks + 1) ^ swz) * 8);
  const int b_hi = (wt + tr) * 64 + (((2 * ks) ^ swz) * 8);
  const int b_lo = (wt + tr) * 64 + (((2 * ks + 1) ^ swz) * 8);
  f32x4 acc[4][4];
#pragma unroll
  for (int i = 0; i < 4; i++)
#pragma unroll
    for (int j = 0; j < 4; j++) acc[i][j] = (f32x4){0.f, 0.f, 0.f, 0.f};
  for (int kt = 0; kt < K; kt += 32) {
    if (kt) __syncthreads();
    const ushort* ga = gA + kt * 2;
    const ushort* gb = gB + kt * 2;
#pragma unroll
    for (int i = 0; i < 4; i++) {
      gl_lds16(ga + (size_t)(i * 8) * pitch, lA + i * 8 * 64);
      gl_lds16(gb + (size_t)(i * 8) * pitch, lB + i * 8 * 64);
    }
    __syncthreads();
    bfx8 ah[4], bh[4], tl[4];
#pragma unroll
    for (int f = 0; f < 4; f++) ah[f] = *(const bfx8*)(As + a_hi + f * 1024);
#pragma unroll
    for (int f = 0; f < 4; f++) bh[f] = *(const bfx8*)(Bs + b_hi + f * 1024);
#pragma unroll
    for (int fi = 0; fi < 4; fi++)
#pragma unroll
      for (int fj = 0; fj < 4; fj++)
        acc[fi][fj] = __builtin_amdgcn_mfma_f32_16x16x32_bf16(ah[fi], bh[fj], acc[fi][fj], 0, 0, 0);
#pragma unroll
    for (int f = 0; f < 4; f++) tl[f] = *(const bfx8*)(Bs + b_lo + f * 1024);
#pragma unroll
    for (int fi = 0; fi < 4; fi++)
#pragma unroll
      for (int fj = 0; fj < 4; fj++)
        acc[fi][fj] = __builtin_amdgcn_mfma_f32_16x16x32_bf16(ah[fi], tl[fj], acc[fi][fj], 0, 0, 0);
#pragma unroll
    for (int f = 0; f < 4; f++) tl[f] = *(const bfx8*)(As + a_lo + f * 1024);
#pragma unroll
    for (int fi = 0; fi < 4; fi++)
#pragma unroll
      for (int fj = 0; fj < 4; fj++)
        acc[fi][fj] = __builtin_amdgcn_mfma_f32_16x16x32_bf16(tl[fi], bh[fj], acc[fi][fj], 0, 0, 0);
  }
  const int orow = ks * 4;
#pragma unroll
  for (int fi = 0; fi < 4; fi++) {
    int m = m0 + wm + fi * 16 + orow;
    if (m >= Mst) continue;
#pragma unroll
    for (int fj = 0; fj < 4; fj++) {
      int t = t0 + wt + fj * 16 + tr;
      float o[4];
#pragma unroll
      for (int i = 0; i < 4; i++) {
        float xv = acc[fi][fj][i];
        if (bias != nullptr && (m + i) < Mb) xv += bias[m + i];
        if (GELU) xv = 0.5f * xv * (1.0f + erff(xv * 0.70710678118654752f));
        o[i] = xv;
      }
      if (OUTBF) {
        size_t base = (size_t)b * c_bs + (size_t)t * (2 * ldc) + ((m >> 3) * 16 + (m & 7));
        ushort hb[4], lb[4];
#pragma unroll
        for (int i = 0; i < 4; i++) {
          float hf = bfhi_f(o[i]);
          hb[i] = (ushort)(__float_as_uint(hf) >> 16);
          lb[i] = f2bf(o[i] - hf);
        }
        *(ushort4*)(Cpk + base) = make_ushort4(hb[0], hb[1], hb[2], hb[3]);
        *(ushort4*)(Cpk + base + 8) = make_ushort4(lb[0], lb[1], lb[2], lb[3]);
      } else {
        *(float4*)(Cf + (size_t)b * c_bs + (size_t)t * ldc + m) =
            make_float4(o[0], o[1], o[2], o[3]);
      }
    }
  }
}

// ------- overlap-add + env normalize + crop, with symmetric frame reconstruction ----
__global__ __launch_bounds__(256) void ola_k(const float* __restrict__ CD,
                                             const double* __restrict__ win,
                                             float* __restrict__ out) {
  size_t flat = (size_t)blockIdx.x * 256 + threadIdx.x;  // over 8*524288
  int b = (int)(flat >> 19);
  int t = (int)(flat & 524287);
  int g = t + 384;  // PAD
  int r = g & 255, q4 = g >> 8;
  double acc = 0.0, env = 0.0;
#pragma unroll
  for (int q = 0; q < 4; q++) {
    int tau = q4 - q;
    int n = r + 256 * q;
    if (tau >= 0 && tau < 2048) {
      double w = win[n];
      int np = (n <= 512) ? n : 1024 - n;
      double sgn = (n <= 512) ? -1.0 : 1.0;
      const float* base = CD + ((size_t)b * 2048 + tau) * 1152 + np;
      acc += (double)base[0] + sgn * (double)base[576];
      env = fma(w, w, env);
    }
  }
  out[flat] = (float)(acc / (env * 1024.0));
}

extern "C" void kernel_launch(void* const* d_in, const int* in_sizes, int n_in, void* d_out,
                              int out_size, void* d_ws, size_t ws_size, hipStream_t stream) {
  (void)in_sizes; (void)n_in; (void)out_size; (void)ws_size;
  const float* x       = (const float*)d_in[0];
  const float* g_out   = (const float*)d_in[1];
  const float* dconv_w = (const float*)d_in[2];
  const float* dconv_b = (const float*)d_in[3];
  const float* p1_w    = (const float*)d_in[4];
  const float* p1_b    = (const float*)d_in[5];
  const float* p1_ain  = (const float*)d_in[6];
  const float* p1_aout = (const float*)d_in[7];
  const float* p2_w    = (const float*)d_in[8];
  const float* p2_b    = (const float*)d_in[9];
  const float* p2_ain  = (const float*)d_in[10];
  const float* p2_aout = (const float*)d_in[11];
  const float* out_w   = (const float*)d_in[12];
  const float* out_b   = (const float*)d_in[13];
  const float* out_ain = (const float*)d_in[14];
  const float* out_aout= (const float*)d_in[15];

  // Workspace: front tables + arena with time-shared slots; peak ~177.1 MB < proven 192.3.
  char* ws = (char*)d_ws;
  float* ain1  = (float*)(ws + 0);         // transposed [b][12][512]
  float* aout1 = (float*)(ws + 196608);
  float* ain2  = (float*)(ws + 786432);    // transposed [b][12][1536]
  float* aout2 = (float*)(ws + 1376256);
  float* ain3  = (float*)(ws + 1572864);   // transposed [b][16][512]
  float* aout3 = (float*)(ws + 1835008);
  ushort* tab  = (ushort*)(ws + 2360320);  // 2 tables * 640*1088*2 B
  double* win  = (double*)(ws + 5145600);
  char*  arena = ws + 5153792;
  ushort* h1  = (ushort*)(arena + 0);
  float*  mp  = (float*)(arena + 0);
  float*  CD  = (float*)(arena + 0);
  ushort* h0  = (ushort*)(arena + 100663296);
  ushort* h2  = (ushort*)(arena + 100663296);
  ushort* w1  = (ushort*)(arena + 134217728);
  ushort* w2  = (ushort*)(arena + 134217728);
  ushort* w3  = (ushort*)(arena + 134217728);
  ushort* Sre = (ushort*)(arena + 100663296);
  ushort* Sim = (ushort*)(arena + 136314880);

  lora_vec_k<<<1536, 256, 0, stream>>>(p1_ain, 6144, g_out, ain1, 512, 12);
  lora_vec_k<<<4608, 256, 0, stream>>>(p1_aout, 18432, g_out, aout1, 0, 0);
  lora_vec_k<<<4608, 256, 0, stream>>>(p2_ain, 18432, g_out, ain2, 1536, 12);
  lora_vec_k<<<1536, 256, 0, stream>>>(p2_aout, 6144, g_out, aout2, 0, 0);
  lora_vec_k<<<2048, 256, 0, stream>>>(out_ain, 8192, g_out, ain3, 512, 16);
  lora_vec_k<<<4104, 256, 0, stream>>>(out_aout, 16416, g_out, aout3, 0, 0);
  atab2_k<<<2720, 256, 0, stream>>>(tab, win);
  dconv_k<<<dim3(32, 8, 8), 256, 0, stream>>>(x, dconv_w, dconv_b, h0);

  // layer 1: h1 = gelu(weff1 . h0 + b1)
  weff_k<<<dim3(384, 1, 8), 256, 0, stream>>>(p1_w, ain1, aout1, w1, 1536, 1536, 512, 12);
  gemm_pk<true, true><<<dim3(12, 16, 8), 256, 0, stream>>>(
      w1, (size_t)1536 * 1024, h0, (size_t)2048 * 1024, p1_b, 1536,
      nullptr, h1, (size_t)2048 * 3072, 1536, 1536, 512);

  // layer 2: h2 = gelu(weff2 . h1 + b2)
  weff_k<<<dim3(384, 1, 8), 256, 0, stream>>>(p2_w, ain2, aout2, w2, 512, 512, 1536, 12);
  gemm_pk<true, true><<<dim3(4, 16, 8), 256, 0, stream>>>(
      w2, (size_t)512 * 3072, h1, (size_t)2048 * 3072, p2_b, 512,
      nullptr, h2, (size_t)2048 * 1024, 512, 512, 1536);

  // output projection: mp = weff3 . h2 + out_b  (fp32 out)
  weff_k<<<dim3(288, 1, 8), 256, 0, stream>>>(out_w, ain3, aout3, w3, 1026, 1152, 512, 16);
  gemm_pk<false, false><<<dim3(9, 16, 8), 256, 0, stream>>>(
      w3, (size_t)1152 * 1024, h2, (size_t)2048 * 1024, out_b, 1026,
      mp, nullptr, (size_t)2048 * SPADK, SPADK, SPADK, 512);

  sprep2_k<<<34816, 256, 0, stream>>>(mp, Sre, Sim);
  // cos-part -> CD[:, :, 0:576], sin-part -> CD[:, :, 576:1152]
  gemm_pk<false, false><<<dim3(5, 16, 8), 256, 0, stream>>>(
      tab, (size_t)0, Sre, (size_t)2048 * ATROW, nullptr, 0,
      CD, nullptr, (size_t)2048 * 1152, 1152, ATMV, ATK);
  gemm_pk<false, false><<<dim3(5, 16, 8), 256, 0, stream>>>(
      tab + ATSZ_PK, (size_t)0, Sim, (size_t)2048 * ATROW, nullptr, 0,
      CD + 576, nullptr, (size_t)2048 * 1152, 1152, ATMV, ATK);
  ola_k<<<16384, 256, 0, stream>>>(CD, win, (float*)d_out);
}